// Round 1
// baseline (2540.866 us; speedup 1.0000x reference)
//
#include <hip/hip_runtime.h>
#include <hip/hip_bf16.h>
#include <math.h>

#define B_ 8
#define T_ 1024
#define D_ 256
#define NH_ 4
#define N_ 256
#define QT 8
#define EPS_ 1e-5f

// ---------- helpers ----------
__device__ inline float2 block_stats_256(float v, float* red) {
    // mean/var over 256 threads (one value per thread). Barrier-safe for reuse.
    float s1 = v, s2 = v * v;
    #pragma unroll
    for (int o = 32; o > 0; o >>= 1) { s1 += __shfl_down(s1, o); s2 += __shfl_down(s2, o); }
    int wave = threadIdx.x >> 6, lane = threadIdx.x & 63;
    __syncthreads();                      // protect red from any previous use
    if (lane == 0) { red[wave] = s1; red[4 + wave] = s2; }
    __syncthreads();
    float S1 = red[0] + red[1] + red[2] + red[3];
    float S2 = red[4] + red[5] + red[6] + red[7];
    float mean = S1 * (1.f / 256.f);
    float var  = S2 * (1.f / 256.f) - mean * mean;
    return make_float2(mean, var);
}

// ---------- input projection + LN:  x[b,t,d] = LN_d(inputs[b,t]*in_w[d] + in_b[d]) ----------
__global__ __launch_bounds__(256) void k_input_ln(
    const float* __restrict__ inputs, const float* __restrict__ in_w,
    const float* __restrict__ in_b, float* __restrict__ x)
{
    __shared__ float red[8];
    int row = blockIdx.x;               // b*T + t
    int d = threadIdx.x;
    float v = inputs[row] * in_w[d] + in_b[d];
    float2 mv = block_stats_256(v, red);
    x[(size_t)row * D_ + d] = (v - mv.x) * rsqrtf(mv.y + EPS_);
}

// ---------- generic fp32 GEMM: C[64x64 tile] = A[M x K] @ W[K x 256] ----------
// MODE 0: encoder   : A = x[b] (lda=256),  out xs[((b*T+m)*NH+h)*N+n] = relu(v)
// MODE 1: encoder_v : A = ykv[b,h] (lda=256), out xs[o] *= relu(v)   (in-place xy)
// MODE 2: decoder   : A = xs as (8192 x 1024), out ymlp[m*256+n] = v
template<int MODE>
__global__ __launch_bounds__(256) void k_gemm(
    const float* __restrict__ Abase, const float* __restrict__ Wbase,
    float* __restrict__ Cbase, int K, int lda)
{
    __shared__ float As[16][64];   // [kk][row]  (transposed for float4 fragment reads)
    __shared__ float Bs[16][64];   // [kk][col]
    int tid = threadIdx.x;
    int bh = blockIdx.z;
    int b = bh >> 2, h = bh & 3;
    const float* A;
    const float* W;
    if (MODE == 2) { A = Abase; W = Wbase; }
    else {
        A = (MODE == 0) ? (Abase + (size_t)b * T_ * D_) : (Abase + (size_t)bh * T_ * D_);
        W = Wbase + (size_t)h * D_ * N_;
    }
    int m0 = blockIdx.y * 64, n0 = blockIdx.x * 64;
    int tx = tid & 15, ty = tid >> 4;
    int ar = tid >> 2, ak = (tid & 3) * 4;   // A-tile load coords
    int bk = tid >> 4, bj = (tid & 15) * 4;  // B-tile load coords
    float acc[4][4] = {};
    for (int k0 = 0; k0 < K; k0 += 16) {
        float4 av = *(const float4*)(A + (size_t)(m0 + ar) * lda + k0 + ak);
        float4 wv = *(const float4*)(W + (size_t)(k0 + bk) * 256 + n0 + bj);
        As[ak + 0][ar] = av.x;
        As[ak + 1][ar] = av.y;
        As[ak + 2][ar] = av.z;
        As[ak + 3][ar] = av.w;
        *(float4*)&Bs[bk][bj] = wv;
        __syncthreads();
        #pragma unroll
        for (int kk = 0; kk < 16; kk++) {
            float4 a  = *(const float4*)&As[kk][ty * 4];
            float4 bv = *(const float4*)&Bs[kk][tx * 4];
            acc[0][0] = fmaf(a.x, bv.x, acc[0][0]); acc[0][1] = fmaf(a.x, bv.y, acc[0][1]);
            acc[0][2] = fmaf(a.x, bv.z, acc[0][2]); acc[0][3] = fmaf(a.x, bv.w, acc[0][3]);
            acc[1][0] = fmaf(a.y, bv.x, acc[1][0]); acc[1][1] = fmaf(a.y, bv.y, acc[1][1]);
            acc[1][2] = fmaf(a.y, bv.z, acc[1][2]); acc[1][3] = fmaf(a.y, bv.w, acc[1][3]);
            acc[2][0] = fmaf(a.z, bv.x, acc[2][0]); acc[2][1] = fmaf(a.z, bv.y, acc[2][1]);
            acc[2][2] = fmaf(a.z, bv.z, acc[2][2]); acc[2][3] = fmaf(a.z, bv.w, acc[2][3]);
            acc[3][0] = fmaf(a.w, bv.x, acc[3][0]); acc[3][1] = fmaf(a.w, bv.y, acc[3][1]);
            acc[3][2] = fmaf(a.w, bv.z, acc[3][2]); acc[3][3] = fmaf(a.w, bv.w, acc[3][3]);
        }
        __syncthreads();
    }
    #pragma unroll
    for (int r = 0; r < 4; r++) {
        int m = m0 + ty * 4 + r;
        int n = n0 + tx * 4;
        if (MODE == 2) {
            *(float4*)&Cbase[(size_t)m * 256 + n] =
                make_float4(acc[r][0], acc[r][1], acc[r][2], acc[r][3]);
        } else {
            size_t o = ((size_t)(b * T_ + m) * NH_ + h) * N_ + n;
            if (MODE == 0) {
                *(float4*)&Cbase[o] = make_float4(fmaxf(acc[r][0], 0.f), fmaxf(acc[r][1], 0.f),
                                                  fmaxf(acc[r][2], 0.f), fmaxf(acc[r][3], 0.f));
            } else {
                float4 old = *(const float4*)&Cbase[o];
                *(float4*)&Cbase[o] = make_float4(old.x * fmaxf(acc[r][0], 0.f),
                                                  old.y * fmaxf(acc[r][1], 0.f),
                                                  old.z * fmaxf(acc[r][2], 0.f),
                                                  old.w * fmaxf(acc[r][3], 0.f));
            }
        }
    }
}

// ---------- rope: xs (B,T,NH,N) -> qrT (B,NH,N,T)  (LDS-tiled transpose) ----------
__global__ __launch_bounds__(256) void k_rope(const float* __restrict__ xs,
                                              float* __restrict__ qrT)
{
    __shared__ float tile[256][33];   // [n][t_local], padded vs bank conflicts
    int gid = blockIdx.x;
    int tt = gid & 31;                // t-tile (32 t's each)
    int bh = gid >> 5;                // 0..31
    int h = bh & 3, b = bh >> 2;
    int t0 = tt * 32;
    int tid = threadIdx.x;
    for (int i = tid; i < 32 * 128; i += 256) {
        int tl = i >> 7;              // 0..31
        int p  = i & 127;             // pair index
        int t  = t0 + tl;
        const float* src = xs + (((size_t)(b * T_ + t) * NH_ + h) << 8) + 2 * p;
        float2 ri = *(const float2*)src;
        int xpos = t & 31, ypos = t >> 5;
        int j   = (p < 64) ? p : p - 64;
        int pos = (p < 64) ? xpos : ypos;
        float f = powf(10000.f, -(float)j * (1.f / 64.f));
        float ang = (float)pos * f;
        float s, c;
        sincosf(ang, &s, &c);
        tile[2 * p][tl]     = ri.x * c - ri.y * s;
        tile[2 * p + 1][tl] = ri.x * s + ri.y * c;
    }
    __syncthreads();
    const size_t base = ((size_t)bh * N_) * T_;
    for (int i = tid; i < 256 * 32; i += 256) {
        int n  = i >> 5;
        int tl = i & 31;
        qrT[base + (size_t)n * T_ + t0 + tl] = tile[n][tl];
    }
}

// ---------- fused attention: scores + softmax + attn@x + LayerNorm ----------
// one block = (b,h, 8 consecutive queries). qrT is (B,NH,N,T).
__global__ __launch_bounds__(256) void k_attn(
    const float* __restrict__ qrT, const float* __restrict__ x,
    float* __restrict__ ykv)
{
    __shared__ float P[QT][T_];      // 32 KB probabilities
    __shared__ float Qs[QT][N_];     // 8 KB query fragments
    __shared__ float red[2 * QT * 4];
    __shared__ float bc[2 * QT];
    int tid = threadIdx.x;
    int gid = blockIdx.x;
    int tile = gid & 127;            // T/QT = 128
    int bh = gid >> 7;               // 0..31
    int b = bh >> 2;
    int t0 = tile * QT;
    const float* KT = qrT + (size_t)bh * N_ * T_;

    for (int i = tid; i < QT * N_; i += 256) {
        int q = i & 7, n = i >> 3;
        Qs[q][n] = KT[(size_t)n * T_ + t0 + q];
    }
    __syncthreads();

    // phase 1: scores[q][s],  s = tid + 256*c
    float acc[QT][4];
    #pragma unroll
    for (int q = 0; q < QT; q++) { acc[q][0] = 0.f; acc[q][1] = 0.f; acc[q][2] = 0.f; acc[q][3] = 0.f; }
    for (int n = 0; n < N_; n++) {
        const float* KTn = KT + (size_t)n * T_;
        float k0 = KTn[tid], k1 = KTn[tid + 256], k2 = KTn[tid + 512], k3 = KTn[tid + 768];
        #pragma unroll
        for (int q = 0; q < QT; q++) {
            float qq = Qs[q][n];
            acc[q][0] = fmaf(qq, k0, acc[q][0]);
            acc[q][1] = fmaf(qq, k1, acc[q][1]);
            acc[q][2] = fmaf(qq, k2, acc[q][2]);
            acc[q][3] = fmaf(qq, k3, acc[q][3]);
        }
    }
    int wave = tid >> 6, lane = tid & 63;
    const float scale = 0.0625f;     // 1/sqrt(256)

    // row max
    #pragma unroll
    for (int q = 0; q < QT; q++) {
        float v = fmaxf(fmaxf(acc[q][0], acc[q][1]), fmaxf(acc[q][2], acc[q][3]));
        #pragma unroll
        for (int o = 32; o > 0; o >>= 1) v = fmaxf(v, __shfl_down(v, o));
        if (lane == 0) red[q * 4 + wave] = v;
    }
    __syncthreads();
    if (tid < QT)
        bc[tid] = fmaxf(fmaxf(red[tid * 4], red[tid * 4 + 1]),
                        fmaxf(red[tid * 4 + 2], red[tid * 4 + 3]));
    __syncthreads();

    // exp + row sum
    #pragma unroll
    for (int q = 0; q < QT; q++) {
        float rm = bc[q];
        float e0 = __expf((acc[q][0] - rm) * scale);
        float e1 = __expf((acc[q][1] - rm) * scale);
        float e2 = __expf((acc[q][2] - rm) * scale);
        float e3 = __expf((acc[q][3] - rm) * scale);
        P[q][tid] = e0; P[q][tid + 256] = e1; P[q][tid + 512] = e2; P[q][tid + 768] = e3;
        float s = e0 + e1 + e2 + e3;
        #pragma unroll
        for (int o = 32; o > 0; o >>= 1) s += __shfl_down(s, o);
        if (lane == 0) red[QT * 4 + q * 4 + wave] = s;
    }
    __syncthreads();
    if (tid < QT)
        bc[QT + tid] = red[QT * 4 + tid * 4] + red[QT * 4 + tid * 4 + 1] +
                       red[QT * 4 + tid * 4 + 2] + red[QT * 4 + tid * 4 + 3];
    __syncthreads();
    float rinv[QT];
    #pragma unroll
    for (int q = 0; q < QT; q++) rinv[q] = 1.f / bc[QT + q];

    // phase 2: yKV[q][d] = sum_s P[q][s] * x[b][s][d],  d = tid
    float acc2[QT] = {};
    const float* xb = x + (size_t)b * T_ * D_;
    for (int s = 0; s < T_; s++) {
        float xv = xb[(size_t)s * D_ + tid];
        #pragma unroll
        for (int q = 0; q < QT; q++) acc2[q] = fmaf(P[q][s], xv, acc2[q]);
    }
    #pragma unroll
    for (int q = 0; q < QT; q++) acc2[q] *= rinv[q];

    // fused LayerNorm over d for each q
    #pragma unroll
    for (int q = 0; q < QT; q++) {
        float a = acc2[q];
        float p1 = a, p2 = a * a;
        #pragma unroll
        for (int o = 32; o > 0; o >>= 1) { p1 += __shfl_down(p1, o); p2 += __shfl_down(p2, o); }
        if (lane == 0) { red[q * 4 + wave] = p1; red[QT * 4 + q * 4 + wave] = p2; }
    }
    __syncthreads();
    if (tid < 2 * QT)
        bc[tid] = red[tid * 4] + red[tid * 4 + 1] + red[tid * 4 + 2] + red[tid * 4 + 3];
    __syncthreads();
    float* out = ykv + ((size_t)bh * T_ + t0) * D_ + tid;
    #pragma unroll
    for (int q = 0; q < QT; q++) {
        float mean = bc[q] * (1.f / 256.f);
        float var  = bc[QT + q] * (1.f / 256.f) - mean * mean;
        out[(size_t)q * D_] = (acc2[q] - mean) * rsqrtf(var + EPS_);
    }
}

// ---------- residual + double LN:  x = LN(x + LN(ymlp)) ----------
__global__ __launch_bounds__(256) void k_resid_ln(float* __restrict__ x,
                                                  const float* __restrict__ ymlp)
{
    __shared__ float red[8];
    int row = blockIdx.x, d = threadIdx.x;
    size_t o = (size_t)row * D_ + d;
    float y = ymlp[o];
    float2 mv1 = block_stats_256(y, red);
    float v = x[o] + (y - mv1.x) * rsqrtf(mv1.y + EPS_);
    float2 mv2 = block_stats_256(v, red);
    x[o] = (v - mv2.x) * rsqrtf(mv2.y + EPS_);
}

// ---------- logits:  out[b,t] = dot(x[b,t,:], out_w) + out_b ----------
__global__ __launch_bounds__(256) void k_logits(
    const float* __restrict__ x, const float* __restrict__ out_w,
    const float* __restrict__ out_b, float* __restrict__ out)
{
    __shared__ float red[4];
    int row = blockIdx.x, d = threadIdx.x;
    float v = x[(size_t)row * D_ + d] * out_w[d];
    #pragma unroll
    for (int o = 32; o > 0; o >>= 1) v += __shfl_down(v, o);
    int wave = d >> 6, lane = d & 63;
    if (lane == 0) red[wave] = v;
    __syncthreads();
    if (d == 0) out[row] = red[0] + red[1] + red[2] + red[3] + out_b[0];
}

extern "C" void kernel_launch(void* const* d_in, const int* in_sizes, int n_in,
                              void* d_out, int out_size, void* d_ws, size_t ws_size,
                              hipStream_t stream)
{
    (void)in_sizes; (void)n_in; (void)out_size;
    if (ws_size < (size_t)112 * 1024 * 1024) return;   // need 112 MB scratch

    const float* inputs    = (const float*)d_in[0];
    const float* in_w      = (const float*)d_in[1];
    const float* in_b      = (const float*)d_in[2];
    const float* encoder   = (const float*)d_in[3];
    const float* encoder_v = (const float*)d_in[4];
    const float* decoder   = (const float*)d_in[5];
    const float* out_w     = (const float*)d_in[6];
    const float* out_b     = (const float*)d_in[7];

    float* x    = (float*)d_ws;                        //  8 MB (B,T,D)
    float* xs   = x    + (size_t)2 * 1024 * 1024;      // 32 MB (B,T,NH,N)  x_sparse / xy
    float* qrT  = xs   + (size_t)8 * 1024 * 1024;      // 32 MB (B,NH,N,T)  rope'd, transposed
    float* ykv  = qrT  + (size_t)8 * 1024 * 1024;      // 32 MB (B,NH,T,D)
    float* ymlp = ykv  + (size_t)8 * 1024 * 1024;      //  8 MB (B,T,D)

    k_input_ln<<<B_ * T_, 256, 0, stream>>>(inputs, in_w, in_b, x);
    for (int l = 0; l < 3; l++) {
        k_gemm<0><<<dim3(4, 16, 32), 256, 0, stream>>>(x, encoder, xs, 256, 256);
        k_rope<<<dim3(1024), 256, 0, stream>>>(xs, qrT);
        k_attn<<<dim3(4096), 256, 0, stream>>>(qrT, x, ykv);
        k_gemm<1><<<dim3(4, 16, 32), 256, 0, stream>>>(ykv, encoder_v, xs, 256, 256);
        k_gemm<2><<<dim3(4, 128, 1), 256, 0, stream>>>(xs, decoder, ymlp, 1024, 1024);
        k_resid_ln<<<B_ * T_, 256, 0, stream>>>(x, ymlp);
    }
    k_logits<<<B_ * T_, 256, 0, stream>>>(x, out_w, out_b, (float*)d_out);
}

// Round 3
// 1682.304 us; speedup vs baseline: 1.5103x; 1.5103x over previous
//
#include <hip/hip_runtime.h>
#include <hip/hip_bf16.h>
#include <math.h>

#define B_ 8
#define T_ 1024
#define D_ 256
#define NH_ 4
#define N_ 256
#define EPS_ 1e-5f

typedef __attribute__((ext_vector_type(8))) short short8_t;
typedef __attribute__((ext_vector_type(4))) float floatx4;

__device__ inline unsigned short f2bf(float f) {
    unsigned u = __builtin_bit_cast(unsigned, f);
    u += 0x7FFFu + ((u >> 16) & 1u);          // round-to-nearest-even
    return (unsigned short)(u >> 16);
}
__device__ inline float bf2f(unsigned short h) {
    return __builtin_bit_cast(float, (unsigned)h << 16);
}

// ---------- helpers ----------
__device__ inline float2 block_stats_256(float v, float* red) {
    float s1 = v, s2 = v * v;
    #pragma unroll
    for (int o = 32; o > 0; o >>= 1) { s1 += __shfl_down(s1, o); s2 += __shfl_down(s2, o); }
    int wave = threadIdx.x >> 6, lane = threadIdx.x & 63;
    __syncthreads();
    if (lane == 0) { red[wave] = s1; red[4 + wave] = s2; }
    __syncthreads();
    float S1 = red[0] + red[1] + red[2] + red[3];
    float S2 = red[4] + red[5] + red[6] + red[7];
    float mean = S1 * (1.f / 256.f);
    float var  = S2 * (1.f / 256.f) - mean * mean;
    return make_float2(mean, var);
}

// ---------- input projection + LN ----------
__global__ __launch_bounds__(256) void k_input_ln(
    const float* __restrict__ inputs, const float* __restrict__ in_w,
    const float* __restrict__ in_b, float* __restrict__ x)
{
    __shared__ float red[8];
    int row = blockIdx.x;
    int d = threadIdx.x;
    float v = inputs[row] * in_w[d] + in_b[d];
    float2 mv = block_stats_256(v, red);
    x[(size_t)row * D_ + d] = (v - mv.x) * rsqrtf(mv.y + EPS_);
}

// ---------- generic fp32 GEMM ----------
template<int MODE>
__global__ __launch_bounds__(256) void k_gemm(
    const float* __restrict__ Abase, const float* __restrict__ Wbase,
    float* __restrict__ Cbase, int K, int lda)
{
    __shared__ float As[16][64];
    __shared__ float Bs[16][64];
    int tid = threadIdx.x;
    int bh = blockIdx.z;
    int b = bh >> 2, h = bh & 3;
    const float* A;
    const float* W;
    if (MODE == 2) { A = Abase; W = Wbase; }
    else {
        A = (MODE == 0) ? (Abase + (size_t)b * T_ * D_) : (Abase + (size_t)bh * T_ * D_);
        W = Wbase + (size_t)h * D_ * N_;
    }
    int m0 = blockIdx.y * 64, n0 = blockIdx.x * 64;
    int tx = tid & 15, ty = tid >> 4;
    int ar = tid >> 2, ak = (tid & 3) * 4;
    int bk = tid >> 4, bj = (tid & 15) * 4;
    float acc[4][4] = {};
    for (int k0 = 0; k0 < K; k0 += 16) {
        float4 av = *(const float4*)(A + (size_t)(m0 + ar) * lda + k0 + ak);
        float4 wv = *(const float4*)(W + (size_t)(k0 + bk) * 256 + n0 + bj);
        As[ak + 0][ar] = av.x;
        As[ak + 1][ar] = av.y;
        As[ak + 2][ar] = av.z;
        As[ak + 3][ar] = av.w;
        *(float4*)&Bs[bk][bj] = wv;
        __syncthreads();
        #pragma unroll
        for (int kk = 0; kk < 16; kk++) {
            float4 a  = *(const float4*)&As[kk][ty * 4];
            float4 bv = *(const float4*)&Bs[kk][tx * 4];
            acc[0][0] = fmaf(a.x, bv.x, acc[0][0]); acc[0][1] = fmaf(a.x, bv.y, acc[0][1]);
            acc[0][2] = fmaf(a.x, bv.z, acc[0][2]); acc[0][3] = fmaf(a.x, bv.w, acc[0][3]);
            acc[1][0] = fmaf(a.y, bv.x, acc[1][0]); acc[1][1] = fmaf(a.y, bv.y, acc[1][1]);
            acc[1][2] = fmaf(a.y, bv.z, acc[1][2]); acc[1][3] = fmaf(a.y, bv.w, acc[1][3]);
            acc[2][0] = fmaf(a.z, bv.x, acc[2][0]); acc[2][1] = fmaf(a.z, bv.y, acc[2][1]);
            acc[2][2] = fmaf(a.z, bv.z, acc[2][2]); acc[2][3] = fmaf(a.z, bv.w, acc[2][3]);
            acc[3][0] = fmaf(a.w, bv.x, acc[3][0]); acc[3][1] = fmaf(a.w, bv.y, acc[3][1]);
            acc[3][2] = fmaf(a.w, bv.z, acc[3][2]); acc[3][3] = fmaf(a.w, bv.w, acc[3][3]);
        }
        __syncthreads();
    }
    #pragma unroll
    for (int r = 0; r < 4; r++) {
        int m = m0 + ty * 4 + r;
        int n = n0 + tx * 4;
        if (MODE == 2) {
            *(float4*)&Cbase[(size_t)m * 256 + n] =
                make_float4(acc[r][0], acc[r][1], acc[r][2], acc[r][3]);
        } else {
            size_t o = ((size_t)(b * T_ + m) * NH_ + h) * N_ + n;
            if (MODE == 0) {
                *(float4*)&Cbase[o] = make_float4(fmaxf(acc[r][0], 0.f), fmaxf(acc[r][1], 0.f),
                                                  fmaxf(acc[r][2], 0.f), fmaxf(acc[r][3], 0.f));
            } else {
                float4 old = *(const float4*)&Cbase[o];
                *(float4*)&Cbase[o] = make_float4(old.x * fmaxf(acc[r][0], 0.f),
                                                  old.y * fmaxf(acc[r][1], 0.f),
                                                  old.z * fmaxf(acc[r][2], 0.f),
                                                  old.w * fmaxf(acc[r][3], 0.f));
            }
        }
    }
}

// ---------- rope: xs (B,T,NH,N) fp32 -> qr hi/lo (B,NH,T,N) bf16 ----------
__global__ __launch_bounds__(256) void k_rope_bf16(
    const float* __restrict__ xs,
    unsigned short* __restrict__ qh, unsigned short* __restrict__ ql)
{
    int tid = blockIdx.x * 256 + threadIdx.x;   // 1M threads, 8 elems each
    int e0 = tid * 8;
    int n0 = e0 & 255;
    int t  = (e0 >> 8) & 1023;
    int bh = e0 >> 18;
    int h = bh & 3, b = bh >> 2;
    const float* src = xs + (((size_t)(b * T_ + t) * NH_ + h) << 8) + n0;
    float4 v0 = *(const float4*)src;
    float4 v1 = *(const float4*)(src + 4);
    float cc[4], ss[4];
    int p0 = n0 >> 1;
    #pragma unroll
    for (int i = 0; i < 4; i++) {
        int p = p0 + i;
        int j = p & 63;
        int pos = (p < 64) ? (t & 31) : (t >> 5);
        float f = powf(10000.f, -(float)j * (1.f / 64.f));
        float ang = (float)pos * f;
        sincosf(ang, &ss[i], &cc[i]);
    }
    float r[8];
    r[0] = v0.x * cc[0] - v0.y * ss[0];
    r[1] = v0.x * ss[0] + v0.y * cc[0];
    r[2] = v0.z * cc[1] - v0.w * ss[1];
    r[3] = v0.z * ss[1] + v0.w * cc[1];
    r[4] = v1.x * cc[2] - v1.y * ss[2];
    r[5] = v1.x * ss[2] + v1.y * cc[2];
    r[6] = v1.z * cc[3] - v1.w * ss[3];
    r[7] = v1.z * ss[3] + v1.w * cc[3];
    short8_t oh, ol;
    #pragma unroll
    for (int i = 0; i < 8; i++) {
        unsigned short hbits = f2bf(r[i]);
        oh[i] = (short)hbits;
        ol[i] = (short)f2bf(r[i] - bf2f(hbits));
    }
    *(short8_t*)(qh + e0) = oh;
    *(short8_t*)(ql + e0) = ol;
}

// ---------- x (B,T,D) fp32 -> xT hi/lo (B,D,T) bf16 ----------
__global__ __launch_bounds__(256) void k_xT(const float* __restrict__ x,
                                            unsigned short* __restrict__ xTh,
                                            unsigned short* __restrict__ xTl)
{
    __shared__ float tile[64][65];
    int t0 = blockIdx.x * 64, d0 = blockIdx.y * 64, b = blockIdx.z;
    const float* src = x + ((size_t)b * T_ + t0) * D_ + d0;
    for (int i = threadIdx.x; i < 1024; i += 256) {
        int r = i >> 4, c = i & 15;
        float4 v = *(const float4*)(src + (size_t)r * D_ + c * 4);
        tile[r][c * 4 + 0] = v.x;
        tile[r][c * 4 + 1] = v.y;
        tile[r][c * 4 + 2] = v.z;
        tile[r][c * 4 + 3] = v.w;
    }
    __syncthreads();
    size_t dbase = ((size_t)b * D_ + d0) * T_ + t0;
    for (int i = threadIdx.x; i < 1024; i += 256) {
        int d = i >> 4, c = i & 15;
        ushort4 oh, ol;
        float v0 = tile[c * 4 + 0][d], v1 = tile[c * 4 + 1][d];
        float v2 = tile[c * 4 + 2][d], v3 = tile[c * 4 + 3][d];
        oh.x = f2bf(v0); ol.x = f2bf(v0 - bf2f(oh.x));
        oh.y = f2bf(v1); ol.y = f2bf(v1 - bf2f(oh.y));
        oh.z = f2bf(v2); ol.z = f2bf(v2 - bf2f(oh.z));
        oh.w = f2bf(v3); ol.w = f2bf(v3 - bf2f(oh.w));
        size_t o = dbase + (size_t)d * T_ + c * 4;
        *(ushort4*)(xTh + o) = oh;
        *(ushort4*)(xTl + o) = ol;
    }
}

// ---------- fused split-bf16 MFMA flash attention + /l + LayerNorm ----------
// block = (b,h, 64-query tile), 4 waves. qr hi/lo (B,NH,T,N), xT hi/lo (B,D,T).
// Split-bf16: A*B ~= Ah*Bh + Ah*Bl + Al*Bh  (residual ~2^-18, fp32-grade).
#define PK 264   // K_lds pitch: 256+8 pad (row=528B==4 banks mod 32 -> free 2-way)
#define PP 72    // P_lds pitch: 64+8  (row=144B==4 banks mod 32 -> free 2-way)

__global__ __launch_bounds__(256, 1) void k_attn_mfma(
    const unsigned short* __restrict__ qr_h, const unsigned short* __restrict__ qr_l,
    const unsigned short* __restrict__ xT_h, const unsigned short* __restrict__ xT_l,
    float* __restrict__ ykv)
{
    __shared__ unsigned short K_h[64 * PK];     // 33792 B
    __shared__ unsigned short K_l[64 * PK];     // 33792 B
    __shared__ unsigned short P_h[64 * PP];     //  9216 B
    __shared__ unsigned short P_l[64 * PP];     //  9216 B
    __shared__ float alpha_lds[64];
    __shared__ float linv_lds[64];
    __shared__ float stat_lds[2][64][4];
    __shared__ float ab_lds[2][64];

    int tid = threadIdx.x;
    int w = tid >> 6, lane = tid & 63, quad = lane >> 4, l16 = lane & 15;
    int gid = blockIdx.x;
    int tile = gid & 15, bh = gid >> 4, b = bh >> 2;
    int t0q = tile * 64;
    const unsigned short* qhb = qr_h + (size_t)bh * T_ * N_;
    const unsigned short* qlb = qr_l + (size_t)bh * T_ * N_;
    const unsigned short* xhb = xT_h + (size_t)b * D_ * T_;
    const unsigned short* xlb = xT_l + (size_t)b * D_ * T_;

    // stage own tile (both planes), pull Q A-frags into registers
    for (int it = 0; it < 8; it++) {
        int fl = tid + it * 256;
        int row = fl >> 5, c16 = fl & 31;
        *(short8_t*)&K_h[row * PK + c16 * 8] =
            *(const short8_t*)(qhb + (size_t)(t0q + row) * N_ + c16 * 8);
        *(short8_t*)&K_l[row * PK + c16 * 8] =
            *(const short8_t*)(qlb + (size_t)(t0q + row) * N_ + c16 * 8);
    }
    __syncthreads();
    short8_t qfh[8], qfl[8];
    #pragma unroll
    for (int kc = 0; kc < 8; kc++) {
        qfh[kc] = *(const short8_t*)&K_h[(w * 16 + l16) * PK + quad * 8 + kc * 32];
        qfl[kc] = *(const short8_t*)&K_l[(w * 16 + l16) * PK + quad * 8 + kc * 32];
    }
    __syncthreads();

    floatx4 O[4][4];
    #pragma unroll
    for (int mt = 0; mt < 4; mt++)
        #pragma unroll
        for (int tn = 0; tn < 4; tn++)
            O[mt][tn] = (floatx4){0.f, 0.f, 0.f, 0.f};
    float Mst[4] = {-1e30f, -1e30f, -1e30f, -1e30f};
    float lst[4] = {0.f, 0.f, 0.f, 0.f};
    const float scale = 0.0625f;   // 1/sqrt(256)

    for (int j = 0; j < 16; j++) {
        // stage K tile j (both planes)
        for (int it = 0; it < 8; it++) {
            int fl = tid + it * 256;
            int row = fl >> 5, c16 = fl & 31;
            *(short8_t*)&K_h[row * PK + c16 * 8] =
                *(const short8_t*)(qhb + (size_t)(j * 64 + row) * N_ + c16 * 8);
            *(short8_t*)&K_l[row * PK + c16 * 8] =
                *(const short8_t*)(qlb + (size_t)(j * 64 + row) * N_ + c16 * 8);
        }
        __syncthreads();

        // QK^T, split 3-term: wave w owns query rows w*16..+16, all 64 kv cols
        floatx4 sc[4];
        #pragma unroll
        for (int ct = 0; ct < 4; ct++) {
            floatx4 acc = (floatx4){0.f, 0.f, 0.f, 0.f};
            #pragma unroll
            for (int kc = 0; kc < 8; kc++) {
                short8_t bkh = *(const short8_t*)&K_h[(ct * 16 + l16) * PK + quad * 8 + kc * 32];
                short8_t bkl = *(const short8_t*)&K_l[(ct * 16 + l16) * PK + quad * 8 + kc * 32];
                acc = __builtin_amdgcn_mfma_f32_16x16x32_bf16(qfh[kc], bkh, acc, 0, 0, 0);
                acc = __builtin_amdgcn_mfma_f32_16x16x32_bf16(qfh[kc], bkl, acc, 0, 0, 0);
                acc = __builtin_amdgcn_mfma_f32_16x16x32_bf16(qfl[kc], bkh, acc, 0, 0, 0);
            }
            sc[ct] = acc;
        }

        // online softmax per row (row = w*16 + quad*4 + r)
        float al[4];
        #pragma unroll
        for (int r = 0; r < 4; r++) {
            float m = fmaxf(fmaxf(sc[0][r], sc[1][r]), fmaxf(sc[2][r], sc[3][r])) * scale;
            #pragma unroll
            for (int o = 1; o < 16; o <<= 1) m = fmaxf(m, __shfl_xor(m, o));
            float Mn = fmaxf(Mst[r], m);
            float alpha = __expf(Mst[r] - Mn);
            Mst[r] = Mn;
            int row = w * 16 + quad * 4 + r;
            float rsum = 0.f;
            #pragma unroll
            for (int ct = 0; ct < 4; ct++) {
                float p = __expf(sc[ct][r] * scale - Mn);
                rsum += p;
                unsigned short ph = f2bf(p);
                P_h[row * PP + ct * 16 + l16] = ph;
                P_l[row * PP + ct * 16 + l16] = f2bf(p - bf2f(ph));
            }
            #pragma unroll
            for (int o = 1; o < 16; o <<= 1) rsum += __shfl_xor(rsum, o);
            lst[r] = lst[r] * alpha + rsum;
            al[r] = alpha;
        }
        if (l16 == 0) {
            #pragma unroll
            for (int r = 0; r < 4; r++) alpha_lds[w * 16 + quad * 4 + r] = al[r];
        }
        __syncthreads();

        // PV, split 3-term: wave w owns d range [w*64, w*64+64), all 64 query rows
        #pragma unroll
        for (int mt = 0; mt < 4; mt++) {
            float af0 = alpha_lds[mt * 16 + quad * 4 + 0];
            float af1 = alpha_lds[mt * 16 + quad * 4 + 1];
            float af2 = alpha_lds[mt * 16 + quad * 4 + 2];
            float af3 = alpha_lds[mt * 16 + quad * 4 + 3];
            #pragma unroll
            for (int tn = 0; tn < 4; tn++) {
                O[mt][tn][0] *= af0; O[mt][tn][1] *= af1;
                O[mt][tn][2] *= af2; O[mt][tn][3] *= af3;
            }
        }
        short8_t vbh[4][2], vbl[4][2];
        #pragma unroll
        for (int tn = 0; tn < 4; tn++)
            #pragma unroll
            for (int kc = 0; kc < 2; kc++) {
                size_t o = (size_t)(w * 64 + tn * 16 + l16) * T_ + j * 64 + quad * 8 + kc * 32;
                vbh[tn][kc] = *(const short8_t*)(xhb + o);
                vbl[tn][kc] = *(const short8_t*)(xlb + o);
            }
        #pragma unroll
        for (int mt = 0; mt < 4; mt++) {
            short8_t pa0h = *(const short8_t*)&P_h[(mt * 16 + l16) * PP + quad * 8];
            short8_t pa1h = *(const short8_t*)&P_h[(mt * 16 + l16) * PP + quad * 8 + 32];
            short8_t pa0l = *(const short8_t*)&P_l[(mt * 16 + l16) * PP + quad * 8];
            short8_t pa1l = *(const short8_t*)&P_l[(mt * 16 + l16) * PP + quad * 8 + 32];
            #pragma unroll
            for (int tn = 0; tn < 4; tn++) {
                O[mt][tn] = __builtin_amdgcn_mfma_f32_16x16x32_bf16(pa0h, vbh[tn][0], O[mt][tn], 0, 0, 0);
                O[mt][tn] = __builtin_amdgcn_mfma_f32_16x16x32_bf16(pa1h, vbh[tn][1], O[mt][tn], 0, 0, 0);
                O[mt][tn] = __builtin_amdgcn_mfma_f32_16x16x32_bf16(pa0h, vbl[tn][0], O[mt][tn], 0, 0, 0);
                O[mt][tn] = __builtin_amdgcn_mfma_f32_16x16x32_bf16(pa1h, vbl[tn][1], O[mt][tn], 0, 0, 0);
                O[mt][tn] = __builtin_amdgcn_mfma_f32_16x16x32_bf16(pa0l, vbh[tn][0], O[mt][tn], 0, 0, 0);
                O[mt][tn] = __builtin_amdgcn_mfma_f32_16x16x32_bf16(pa1l, vbh[tn][1], O[mt][tn], 0, 0, 0);
            }
        }
        __syncthreads();
    }

    // epilogue: yKV = LN_d(O / l)
    if (l16 == 0) {
        #pragma unroll
        for (int r = 0; r < 4; r++) linv_lds[w * 16 + quad * 4 + r] = 1.f / lst[r];
    }
    #pragma unroll
    for (int mt = 0; mt < 4; mt++) {
        #pragma unroll
        for (int r = 0; r < 4; r++) {
            float a0 = O[mt][0][r], a1 = O[mt][1][r], a2 = O[mt][2][r], a3 = O[mt][3][r];
            float s1 = a0 + a1 + a2 + a3;
            float s2 = a0 * a0 + a1 * a1 + a2 * a2 + a3 * a3;
            #pragma unroll
            for (int o = 1; o < 16; o <<= 1) { s1 += __shfl_xor(s1, o); s2 += __shfl_xor(s2, o); }
            if (l16 == 0) {
                stat_lds[0][mt * 16 + quad * 4 + r][w] = s1;
                stat_lds[1][mt * 16 + quad * 4 + r][w] = s2;
            }
        }
    }
    __syncthreads();
    if (tid < 64) {
        float li = linv_lds[tid];
        float S1 = stat_lds[0][tid][0] + stat_lds[0][tid][1] + stat_lds[0][tid][2] + stat_lds[0][tid][3];
        float S2 = stat_lds[1][tid][0] + stat_lds[1][tid][1] + stat_lds[1][tid][2] + stat_lds[1][tid][3];
        float mean = S1 * li * (1.f / 256.f);
        float e2   = S2 * li * li * (1.f / 256.f);
        float var  = e2 - mean * mean;
        float rs = rsqrtf(var + EPS_);
        ab_lds[0][tid] = li * rs;
        ab_lds[1][tid] = mean * rs;
    }
    __syncthreads();
    float* outp = ykv + ((size_t)bh * T_ + t0q) * D_;
    #pragma unroll
    for (int mt = 0; mt < 4; mt++) {
        #pragma unroll
        for (int r = 0; r < 4; r++) {
            int row = mt * 16 + quad * 4 + r;
            float a = ab_lds[0][row], bb = ab_lds[1][row];
            #pragma unroll
            for (int tn = 0; tn < 4; tn++)
                outp[(size_t)row * D_ + w * 64 + tn * 16 + l16] = O[mt][tn][r] * a - bb;
        }
    }
}

// ---------- residual + double LN ----------
__global__ __launch_bounds__(256) void k_resid_ln(float* __restrict__ x,
                                                  const float* __restrict__ ymlp)
{
    __shared__ float red[8];
    int row = blockIdx.x, d = threadIdx.x;
    size_t o = (size_t)row * D_ + d;
    float y = ymlp[o];
    float2 mv1 = block_stats_256(y, red);
    float v = x[o] + (y - mv1.x) * rsqrtf(mv1.y + EPS_);
    float2 mv2 = block_stats_256(v, red);
    x[o] = (v - mv2.x) * rsqrtf(mv2.y + EPS_);
}

// ---------- logits ----------
__global__ __launch_bounds__(256) void k_logits(
    const float* __restrict__ x, const float* __restrict__ out_w,
    const float* __restrict__ out_b, float* __restrict__ out)
{
    __shared__ float red[4];
    int row = blockIdx.x, d = threadIdx.x;
    float v = x[(size_t)row * D_ + d] * out_w[d];
    #pragma unroll
    for (int o = 32; o > 0; o >>= 1) v += __shfl_down(v, o);
    int wave = d >> 6, lane = d & 63;
    if (lane == 0) red[wave] = v;
    __syncthreads();
    if (d == 0) out[row] = red[0] + red[1] + red[2] + red[3] + out_b[0];
}

extern "C" void kernel_launch(void* const* d_in, const int* in_sizes, int n_in,
                              void* d_out, int out_size, void* d_ws, size_t ws_size,
                              hipStream_t stream)
{
    (void)in_sizes; (void)n_in; (void)out_size;
    if (ws_size < (size_t)112 * 1024 * 1024) return;

    const float* inputs    = (const float*)d_in[0];
    const float* in_w      = (const float*)d_in[1];
    const float* in_b      = (const float*)d_in[2];
    const float* encoder   = (const float*)d_in[3];
    const float* encoder_v = (const float*)d_in[4];
    const float* decoder   = (const float*)d_in[5];
    const float* out_w     = (const float*)d_in[6];
    const float* out_b     = (const float*)d_in[7];

    char* wsb = (char*)d_ws;
    float* x            = (float*)(wsb);                               //  8 MB (B,T,D)
    float* xs           = (float*)(wsb + ((size_t)8  << 20));          // 32 MB (B,T,NH,N)
    float* ykv          = (float*)(wsb + ((size_t)40 << 20));          // 32 MB (B,NH,T,D)
    unsigned short* qr_h = (unsigned short*)(wsb + ((size_t)72 << 20)); // 16 MB bf16 hi
    float* ymlp         = (float*)(wsb + ((size_t)72 << 20));          //  8 MB, ALIASES qr_h
                                                                       //  (qr dead after attn;
                                                                       //   rope rewrites next layer)
    unsigned short* qr_l = (unsigned short*)(wsb + ((size_t)88 << 20)); // 16 MB bf16 lo
    unsigned short* xT_h = (unsigned short*)(wsb + ((size_t)104 << 20)); // 4 MB bf16 (B,D,T) hi
    unsigned short* xT_l = (unsigned short*)(wsb + ((size_t)108 << 20)); // 4 MB bf16 (B,D,T) lo

    k_input_ln<<<B_ * T_, 256, 0, stream>>>(inputs, in_w, in_b, x);
    for (int l = 0; l < 3; l++) {
        k_gemm<0><<<dim3(4, 16, 32), 256, 0, stream>>>(x, encoder, xs, 256, 256);
        k_rope_bf16<<<4096, 256, 0, stream>>>(xs, qr_h, qr_l);
        k_xT<<<dim3(16, 4, 8), 256, 0, stream>>>(x, xT_h, xT_l);
        k_attn_mfma<<<512, 256, 0, stream>>>(qr_h, qr_l, xT_h, xT_l, ykv);
        k_gemm<1><<<dim3(4, 16, 32), 256, 0, stream>>>(ykv, encoder_v, xs, 256, 256);
        k_gemm<2><<<dim3(4, 128, 1), 256, 0, stream>>>(xs, decoder, ymlp, 1024, 1024);
        k_resid_ln<<<B_ * T_, 256, 0, stream>>>(x, ymlp);
    }
    k_logits<<<B_ * T_, 256, 0, stream>>>(x, out_w, out_b, (float*)d_out);
}

// Round 4
// 1592.674 us; speedup vs baseline: 1.5953x; 1.0563x over previous
//
#include <hip/hip_runtime.h>
#include <hip/hip_bf16.h>
#include <math.h>

#define B_ 8
#define T_ 1024
#define D_ 256
#define NH_ 4
#define N_ 256
#define EPS_ 1e-5f

typedef __attribute__((ext_vector_type(8))) short short8_t;
typedef __attribute__((ext_vector_type(4))) float floatx4;

__device__ inline unsigned short f2bf(float f) {
    unsigned u = __builtin_bit_cast(unsigned, f);
    u += 0x7FFFu + ((u >> 16) & 1u);          // round-to-nearest-even
    return (unsigned short)(u >> 16);
}
__device__ inline float bf2f(unsigned short h) {
    return __builtin_bit_cast(float, (unsigned)h << 16);
}

// ---------- helpers ----------
__device__ inline float2 block_stats_256(float v, float* red) {
    float s1 = v, s2 = v * v;
    #pragma unroll
    for (int o = 32; o > 0; o >>= 1) { s1 += __shfl_down(s1, o); s2 += __shfl_down(s2, o); }
    int wave = threadIdx.x >> 6, lane = threadIdx.x & 63;
    __syncthreads();
    if (lane == 0) { red[wave] = s1; red[4 + wave] = s2; }
    __syncthreads();
    float S1 = red[0] + red[1] + red[2] + red[3];
    float S2 = red[4] + red[5] + red[6] + red[7];
    float mean = S1 * (1.f / 256.f);
    float var  = S2 * (1.f / 256.f) - mean * mean;
    return make_float2(mean, var);
}

// ---------- input projection + LN ----------
__global__ __launch_bounds__(256) void k_input_ln(
    const float* __restrict__ inputs, const float* __restrict__ in_w,
    const float* __restrict__ in_b, float* __restrict__ x)
{
    __shared__ float red[8];
    int row = blockIdx.x;
    int d = threadIdx.x;
    float v = inputs[row] * in_w[d] + in_b[d];
    float2 mv = block_stats_256(v, red);
    x[(size_t)row * D_ + d] = (v - mv.x) * rsqrtf(mv.y + EPS_);
}

// ---------- generic fp32 GEMM ----------
template<int MODE>
__global__ __launch_bounds__(256) void k_gemm(
    const float* __restrict__ Abase, const float* __restrict__ Wbase,
    float* __restrict__ Cbase, int K, int lda)
{
    __shared__ float As[16][64];
    __shared__ float Bs[16][64];
    int tid = threadIdx.x;
    int bh = blockIdx.z;
    int b = bh >> 2, h = bh & 3;
    const float* A;
    const float* W;
    if (MODE == 2) { A = Abase; W = Wbase; }
    else {
        A = (MODE == 0) ? (Abase + (size_t)b * T_ * D_) : (Abase + (size_t)bh * T_ * D_);
        W = Wbase + (size_t)h * D_ * N_;
    }
    int m0 = blockIdx.y * 64, n0 = blockIdx.x * 64;
    int tx = tid & 15, ty = tid >> 4;
    int ar = tid >> 2, ak = (tid & 3) * 4;
    int bk = tid >> 4, bj = (tid & 15) * 4;
    float acc[4][4] = {};
    for (int k0 = 0; k0 < K; k0 += 16) {
        float4 av = *(const float4*)(A + (size_t)(m0 + ar) * lda + k0 + ak);
        float4 wv = *(const float4*)(W + (size_t)(k0 + bk) * 256 + n0 + bj);
        As[ak + 0][ar] = av.x;
        As[ak + 1][ar] = av.y;
        As[ak + 2][ar] = av.z;
        As[ak + 3][ar] = av.w;
        *(float4*)&Bs[bk][bj] = wv;
        __syncthreads();
        #pragma unroll
        for (int kk = 0; kk < 16; kk++) {
            float4 a  = *(const float4*)&As[kk][ty * 4];
            float4 bv = *(const float4*)&Bs[kk][tx * 4];
            acc[0][0] = fmaf(a.x, bv.x, acc[0][0]); acc[0][1] = fmaf(a.x, bv.y, acc[0][1]);
            acc[0][2] = fmaf(a.x, bv.z, acc[0][2]); acc[0][3] = fmaf(a.x, bv.w, acc[0][3]);
            acc[1][0] = fmaf(a.y, bv.x, acc[1][0]); acc[1][1] = fmaf(a.y, bv.y, acc[1][1]);
            acc[1][2] = fmaf(a.y, bv.z, acc[1][2]); acc[1][3] = fmaf(a.y, bv.w, acc[1][3]);
            acc[2][0] = fmaf(a.z, bv.x, acc[2][0]); acc[2][1] = fmaf(a.z, bv.y, acc[2][1]);
            acc[2][2] = fmaf(a.z, bv.z, acc[2][2]); acc[2][3] = fmaf(a.z, bv.w, acc[2][3]);
            acc[3][0] = fmaf(a.w, bv.x, acc[3][0]); acc[3][1] = fmaf(a.w, bv.y, acc[3][1]);
            acc[3][2] = fmaf(a.w, bv.z, acc[3][2]); acc[3][3] = fmaf(a.w, bv.w, acc[3][3]);
        }
        __syncthreads();
    }
    #pragma unroll
    for (int r = 0; r < 4; r++) {
        int m = m0 + ty * 4 + r;
        int n = n0 + tx * 4;
        if (MODE == 2) {
            *(float4*)&Cbase[(size_t)m * 256 + n] =
                make_float4(acc[r][0], acc[r][1], acc[r][2], acc[r][3]);
        } else {
            size_t o = ((size_t)(b * T_ + m) * NH_ + h) * N_ + n;
            if (MODE == 0) {
                *(float4*)&Cbase[o] = make_float4(fmaxf(acc[r][0], 0.f), fmaxf(acc[r][1], 0.f),
                                                  fmaxf(acc[r][2], 0.f), fmaxf(acc[r][3], 0.f));
            } else {
                float4 old = *(const float4*)&Cbase[o];
                *(float4*)&Cbase[o] = make_float4(old.x * fmaxf(acc[r][0], 0.f),
                                                  old.y * fmaxf(acc[r][1], 0.f),
                                                  old.z * fmaxf(acc[r][2], 0.f),
                                                  old.w * fmaxf(acc[r][3], 0.f));
            }
        }
    }
}

// ---------- rope: xs (B,T,NH,N) fp32 -> qr hi/lo (B,NH,T,N) bf16 ----------
__global__ __launch_bounds__(256) void k_rope_bf16(
    const float* __restrict__ xs,
    unsigned short* __restrict__ qh, unsigned short* __restrict__ ql)
{
    int tid = blockIdx.x * 256 + threadIdx.x;   // 1M threads, 8 elems each
    int e0 = tid * 8;
    int n0 = e0 & 255;
    int t  = (e0 >> 8) & 1023;
    int bh = e0 >> 18;
    int h = bh & 3, b = bh >> 2;
    const float* src = xs + (((size_t)(b * T_ + t) * NH_ + h) << 8) + n0;
    float4 v0 = *(const float4*)src;
    float4 v1 = *(const float4*)(src + 4);
    float cc[4], ss[4];
    int p0 = n0 >> 1;
    #pragma unroll
    for (int i = 0; i < 4; i++) {
        int p = p0 + i;
        int j = p & 63;
        int pos = (p < 64) ? (t & 31) : (t >> 5);
        float f = powf(10000.f, -(float)j * (1.f / 64.f));
        float ang = (float)pos * f;
        sincosf(ang, &ss[i], &cc[i]);
    }
    float r[8];
    r[0] = v0.x * cc[0] - v0.y * ss[0];
    r[1] = v0.x * ss[0] + v0.y * cc[0];
    r[2] = v0.z * cc[1] - v0.w * ss[1];
    r[3] = v0.z * ss[1] + v0.w * cc[1];
    r[4] = v1.x * cc[2] - v1.y * ss[2];
    r[5] = v1.x * ss[2] + v1.y * cc[2];
    r[6] = v1.z * cc[3] - v1.w * ss[3];
    r[7] = v1.z * ss[3] + v1.w * cc[3];
    short8_t oh, ol;
    #pragma unroll
    for (int i = 0; i < 8; i++) {
        unsigned short hbits = f2bf(r[i]);
        oh[i] = (short)hbits;
        ol[i] = (short)f2bf(r[i] - bf2f(hbits));
    }
    *(short8_t*)(qh + e0) = oh;
    *(short8_t*)(ql + e0) = ol;
}

// ---------- x (B,T,D) fp32 -> xT hi/lo (B,D,T) bf16 ----------
__global__ __launch_bounds__(256) void k_xT(const float* __restrict__ x,
                                            unsigned short* __restrict__ xTh,
                                            unsigned short* __restrict__ xTl)
{
    __shared__ float tile[64][65];
    int t0 = blockIdx.x * 64, d0 = blockIdx.y * 64, b = blockIdx.z;
    const float* src = x + ((size_t)b * T_ + t0) * D_ + d0;
    for (int i = threadIdx.x; i < 1024; i += 256) {
        int r = i >> 4, c = i & 15;
        float4 v = *(const float4*)(src + (size_t)r * D_ + c * 4);
        tile[r][c * 4 + 0] = v.x;
        tile[r][c * 4 + 1] = v.y;
        tile[r][c * 4 + 2] = v.z;
        tile[r][c * 4 + 3] = v.w;
    }
    __syncthreads();
    size_t dbase = ((size_t)b * D_ + d0) * T_ + t0;
    for (int i = threadIdx.x; i < 1024; i += 256) {
        int d = i >> 4, c = i & 15;
        ushort4 oh, ol;
        float v0 = tile[c * 4 + 0][d], v1 = tile[c * 4 + 1][d];
        float v2 = tile[c * 4 + 2][d], v3 = tile[c * 4 + 3][d];
        oh.x = f2bf(v0); ol.x = f2bf(v0 - bf2f(oh.x));
        oh.y = f2bf(v1); ol.y = f2bf(v1 - bf2f(oh.y));
        oh.z = f2bf(v2); ol.z = f2bf(v2 - bf2f(oh.z));
        oh.w = f2bf(v3); ol.w = f2bf(v3 - bf2f(oh.w));
        size_t o = dbase + (size_t)d * T_ + c * 4;
        *(ushort4*)(xTh + o) = oh;
        *(ushort4*)(xTl + o) = ol;
    }
}

// ---------- fused split-bf16 MFMA flash attention + /l + LayerNorm ----------
// block = (b,h, 128-query tile), 8 waves (2 waves/SIMD). K tile shared by both
// 64-q halves; next-K register prefetch overlaps global latency with compute.
// QK: wave w owns q rows w*16..+16.  PV: wave w owns q-half (w>>2), d (w&3)*64.
#define PK 264   // K_lds pitch: 256+8 pad (row=528B==4 banks mod 32 -> free 2-way)
#define PP 72    // P_lds pitch: 64+8  (row=144B)

__global__ __launch_bounds__(512, 2) void k_attn_mfma(
    const unsigned short* __restrict__ qr_h, const unsigned short* __restrict__ qr_l,
    const unsigned short* __restrict__ xT_h, const unsigned short* __restrict__ xT_l,
    float* __restrict__ ykv)
{
    __shared__ unsigned short K_h[64 * PK];      // 33792 B
    __shared__ unsigned short K_l[64 * PK];      // 33792 B
    __shared__ unsigned short P_h[128 * PP];     // 18432 B
    __shared__ unsigned short P_l[128 * PP];     // 18432 B
    __shared__ float alpha_lds[128];
    __shared__ float linv_lds[128];
    __shared__ float stat_lds[2][128][4];
    __shared__ float ab_lds[2][128];

    int tid = threadIdx.x;
    int w = tid >> 6, lane = tid & 63, quad = lane >> 4, l16 = lane & 15;
    int h2 = w >> 2, qw = w & 3;                 // PV role
    int gid = blockIdx.x;
    int tile = gid & 7, bh = gid >> 3, b = bh >> 2;
    int t0q = tile * 128;
    const unsigned short* qhb = qr_h + (size_t)bh * T_ * N_;
    const unsigned short* qlb = qr_l + (size_t)bh * T_ * N_;
    const unsigned short* xhb = xT_h + (size_t)b * D_ * T_;
    const unsigned short* xlb = xT_l + (size_t)b * D_ * T_;

    // Q A-frags straight from global (once; L2-hot)
    short8_t qfh[8], qfl[8];
    #pragma unroll
    for (int kc = 0; kc < 8; kc++) {
        size_t o = (size_t)(t0q + w * 16 + l16) * N_ + quad * 8 + kc * 32;
        qfh[kc] = *(const short8_t*)(qhb + o);
        qfl[kc] = *(const short8_t*)(qlb + o);
    }

    // prefetch K tile 0 into registers
    short8_t pre_h[4], pre_l[4];
    #pragma unroll
    for (int it = 0; it < 4; it++) {
        int fl = tid + it * 512;
        int row = fl >> 5, c16 = fl & 31;
        pre_h[it] = *(const short8_t*)(qhb + (size_t)row * N_ + c16 * 8);
        pre_l[it] = *(const short8_t*)(qlb + (size_t)row * N_ + c16 * 8);
    }

    floatx4 O[4][4];
    #pragma unroll
    for (int mt = 0; mt < 4; mt++)
        #pragma unroll
        for (int tn = 0; tn < 4; tn++)
            O[mt][tn] = (floatx4){0.f, 0.f, 0.f, 0.f};
    float Mst[4] = {-1e30f, -1e30f, -1e30f, -1e30f};
    float lst[4] = {0.f, 0.f, 0.f, 0.f};
    const float scale = 0.0625f;   // 1/sqrt(256)

    for (int j = 0; j < 16; j++) {
        // commit prefetched K tile to LDS
        #pragma unroll
        for (int it = 0; it < 4; it++) {
            int fl = tid + it * 512;
            int row = fl >> 5, c16 = fl & 31;
            *(short8_t*)&K_h[row * PK + c16 * 8] = pre_h[it];
            *(short8_t*)&K_l[row * PK + c16 * 8] = pre_l[it];
        }
        __syncthreads();
        // issue prefetch for next tile (overlaps with QK+softmax+PV)
        if (j < 15) {
            #pragma unroll
            for (int it = 0; it < 4; it++) {
                int fl = tid + it * 512;
                int row = fl >> 5, c16 = fl & 31;
                pre_h[it] = *(const short8_t*)(qhb + (size_t)((j + 1) * 64 + row) * N_ + c16 * 8);
                pre_l[it] = *(const short8_t*)(qlb + (size_t)((j + 1) * 64 + row) * N_ + c16 * 8);
            }
        }

        // QK^T, split 3-term: wave w owns q rows w*16..+16, all 64 kv cols
        floatx4 sc[4];
        #pragma unroll
        for (int ct = 0; ct < 4; ct++) {
            floatx4 acc = (floatx4){0.f, 0.f, 0.f, 0.f};
            #pragma unroll
            for (int kc = 0; kc < 8; kc++) {
                short8_t bkh = *(const short8_t*)&K_h[(ct * 16 + l16) * PK + quad * 8 + kc * 32];
                short8_t bkl = *(const short8_t*)&K_l[(ct * 16 + l16) * PK + quad * 8 + kc * 32];
                acc = __builtin_amdgcn_mfma_f32_16x16x32_bf16(qfh[kc], bkh, acc, 0, 0, 0);
                acc = __builtin_amdgcn_mfma_f32_16x16x32_bf16(qfh[kc], bkl, acc, 0, 0, 0);
                acc = __builtin_amdgcn_mfma_f32_16x16x32_bf16(qfl[kc], bkh, acc, 0, 0, 0);
            }
            sc[ct] = acc;
        }

        // online softmax per row (row = w*16 + quad*4 + r)
        float al[4];
        #pragma unroll
        for (int r = 0; r < 4; r++) {
            float m = fmaxf(fmaxf(sc[0][r], sc[1][r]), fmaxf(sc[2][r], sc[3][r])) * scale;
            #pragma unroll
            for (int o = 1; o < 16; o <<= 1) m = fmaxf(m, __shfl_xor(m, o));
            float Mn = fmaxf(Mst[r], m);
            float alpha = __expf(Mst[r] - Mn);
            Mst[r] = Mn;
            int row = w * 16 + quad * 4 + r;
            float rsum = 0.f;
            #pragma unroll
            for (int ct = 0; ct < 4; ct++) {
                float p = __expf(sc[ct][r] * scale - Mn);
                rsum += p;
                unsigned short ph = f2bf(p);
                P_h[row * PP + ct * 16 + l16] = ph;
                P_l[row * PP + ct * 16 + l16] = f2bf(p - bf2f(ph));
            }
            #pragma unroll
            for (int o = 1; o < 16; o <<= 1) rsum += __shfl_xor(rsum, o);
            lst[r] = lst[r] * alpha + rsum;
            al[r] = alpha;
        }
        if (l16 == 0) {
            #pragma unroll
            for (int r = 0; r < 4; r++) alpha_lds[w * 16 + quad * 4 + r] = al[r];
        }
        __syncthreads();

        // PV, split 3-term: wave w owns q-half h2 (rows h2*64..+64), d range qw*64..+64
        #pragma unroll
        for (int mt = 0; mt < 4; mt++) {
            float af0 = alpha_lds[h2 * 64 + mt * 16 + quad * 4 + 0];
            float af1 = alpha_lds[h2 * 64 + mt * 16 + quad * 4 + 1];
            float af2 = alpha_lds[h2 * 64 + mt * 16 + quad * 4 + 2];
            float af3 = alpha_lds[h2 * 64 + mt * 16 + quad * 4 + 3];
            #pragma unroll
            for (int tn = 0; tn < 4; tn++) {
                O[mt][tn][0] *= af0; O[mt][tn][1] *= af1;
                O[mt][tn][2] *= af2; O[mt][tn][3] *= af3;
            }
        }
        short8_t vbh[4][2], vbl[4][2];
        #pragma unroll
        for (int tn = 0; tn < 4; tn++)
            #pragma unroll
            for (int kc = 0; kc < 2; kc++) {
                size_t o = (size_t)(qw * 64 + tn * 16 + l16) * T_ + j * 64 + quad * 8 + kc * 32;
                vbh[tn][kc] = *(const short8_t*)(xhb + o);
                vbl[tn][kc] = *(const short8_t*)(xlb + o);
            }
        #pragma unroll
        for (int mt = 0; mt < 4; mt++) {
            int prow = h2 * 64 + mt * 16 + l16;
            short8_t pa0h = *(const short8_t*)&P_h[prow * PP + quad * 8];
            short8_t pa1h = *(const short8_t*)&P_h[prow * PP + quad * 8 + 32];
            short8_t pa0l = *(const short8_t*)&P_l[prow * PP + quad * 8];
            short8_t pa1l = *(const short8_t*)&P_l[prow * PP + quad * 8 + 32];
            #pragma unroll
            for (int tn = 0; tn < 4; tn++) {
                O[mt][tn] = __builtin_amdgcn_mfma_f32_16x16x32_bf16(pa0h, vbh[tn][0], O[mt][tn], 0, 0, 0);
                O[mt][tn] = __builtin_amdgcn_mfma_f32_16x16x32_bf16(pa1h, vbh[tn][1], O[mt][tn], 0, 0, 0);
                O[mt][tn] = __builtin_amdgcn_mfma_f32_16x16x32_bf16(pa0h, vbl[tn][0], O[mt][tn], 0, 0, 0);
                O[mt][tn] = __builtin_amdgcn_mfma_f32_16x16x32_bf16(pa1h, vbl[tn][1], O[mt][tn], 0, 0, 0);
                O[mt][tn] = __builtin_amdgcn_mfma_f32_16x16x32_bf16(pa0l, vbh[tn][0], O[mt][tn], 0, 0, 0);
                O[mt][tn] = __builtin_amdgcn_mfma_f32_16x16x32_bf16(pa1l, vbh[tn][1], O[mt][tn], 0, 0, 0);
            }
        }
        __syncthreads();
    }

    // epilogue: yKV = LN_d(O / l)
    if (l16 == 0) {
        #pragma unroll
        for (int r = 0; r < 4; r++) linv_lds[w * 16 + quad * 4 + r] = 1.f / lst[r];
    }
    #pragma unroll
    for (int mt = 0; mt < 4; mt++) {
        #pragma unroll
        for (int r = 0; r < 4; r++) {
            float a0 = O[mt][0][r], a1 = O[mt][1][r], a2 = O[mt][2][r], a3 = O[mt][3][r];
            float s1 = a0 + a1 + a2 + a3;
            float s2 = a0 * a0 + a1 * a1 + a2 * a2 + a3 * a3;
            #pragma unroll
            for (int o = 1; o < 16; o <<= 1) { s1 += __shfl_xor(s1, o); s2 += __shfl_xor(s2, o); }
            if (l16 == 0) {
                stat_lds[0][h2 * 64 + mt * 16 + quad * 4 + r][qw] = s1;
                stat_lds[1][h2 * 64 + mt * 16 + quad * 4 + r][qw] = s2;
            }
        }
    }
    __syncthreads();
    if (tid < 128) {
        float li = linv_lds[tid];
        float S1 = stat_lds[0][tid][0] + stat_lds[0][tid][1] + stat_lds[0][tid][2] + stat_lds[0][tid][3];
        float S2 = stat_lds[1][tid][0] + stat_lds[1][tid][1] + stat_lds[1][tid][2] + stat_lds[1][tid][3];
        float mean = S1 * li * (1.f / 256.f);
        float e2   = S2 * li * li * (1.f / 256.f);
        float var  = e2 - mean * mean;
        float rs = rsqrtf(var + EPS_);
        ab_lds[0][tid] = li * rs;
        ab_lds[1][tid] = mean * rs;
    }
    __syncthreads();
    float* outp = ykv + ((size_t)bh * T_ + t0q) * D_;
    #pragma unroll
    for (int mt = 0; mt < 4; mt++) {
        #pragma unroll
        for (int r = 0; r < 4; r++) {
            int row = h2 * 64 + mt * 16 + quad * 4 + r;
            float a = ab_lds[0][row], bb = ab_lds[1][row];
            #pragma unroll
            for (int tn = 0; tn < 4; tn++)
                outp[(size_t)row * D_ + qw * 64 + tn * 16 + l16] = O[mt][tn][r] * a - bb;
        }
    }
}

// ---------- residual + double LN ----------
__global__ __launch_bounds__(256) void k_resid_ln(float* __restrict__ x,
                                                  const float* __restrict__ ymlp)
{
    __shared__ float red[8];
    int row = blockIdx.x, d = threadIdx.x;
    size_t o = (size_t)row * D_ + d;
    float y = ymlp[o];
    float2 mv1 = block_stats_256(y, red);
    float v = x[o] + (y - mv1.x) * rsqrtf(mv1.y + EPS_);
    float2 mv2 = block_stats_256(v, red);
    x[o] = (v - mv2.x) * rsqrtf(mv2.y + EPS_);
}

// ---------- logits ----------
__global__ __launch_bounds__(256) void k_logits(
    const float* __restrict__ x, const float* __restrict__ out_w,
    const float* __restrict__ out_b, float* __restrict__ out)
{
    __shared__ float red[4];
    int row = blockIdx.x, d = threadIdx.x;
    float v = x[(size_t)row * D_ + d] * out_w[d];
    #pragma unroll
    for (int o = 32; o > 0; o >>= 1) v += __shfl_down(v, o);
    int wave = d >> 6, lane = d & 63;
    if (lane == 0) red[wave] = v;
    __syncthreads();
    if (d == 0) out[row] = red[0] + red[1] + red[2] + red[3] + out_b[0];
}

extern "C" void kernel_launch(void* const* d_in, const int* in_sizes, int n_in,
                              void* d_out, int out_size, void* d_ws, size_t ws_size,
                              hipStream_t stream)
{
    (void)in_sizes; (void)n_in; (void)out_size;
    if (ws_size < (size_t)112 * 1024 * 1024) return;

    const float* inputs    = (const float*)d_in[0];
    const float* in_w      = (const float*)d_in[1];
    const float* in_b      = (const float*)d_in[2];
    const float* encoder   = (const float*)d_in[3];
    const float* encoder_v = (const float*)d_in[4];
    const float* decoder   = (const float*)d_in[5];
    const float* out_w     = (const float*)d_in[6];
    const float* out_b     = (const float*)d_in[7];

    char* wsb = (char*)d_ws;
    float* x            = (float*)(wsb);                               //  8 MB (B,T,D)
    float* xs           = (float*)(wsb + ((size_t)8  << 20));          // 32 MB (B,T,NH,N)
    float* ykv          = (float*)(wsb + ((size_t)40 << 20));          // 32 MB (B,NH,T,D)
    unsigned short* qr_h = (unsigned short*)(wsb + ((size_t)72 << 20)); // 16 MB bf16 hi
    float* ymlp         = (float*)(wsb + ((size_t)72 << 20));          //  8 MB, ALIASES qr_h
                                                                       //  (qr dead after attn;
                                                                       //   rope rewrites next layer)
    unsigned short* qr_l = (unsigned short*)(wsb + ((size_t)88 << 20)); // 16 MB bf16 lo
    unsigned short* xT_h = (unsigned short*)(wsb + ((size_t)104 << 20)); // 4 MB bf16 (B,D,T) hi
    unsigned short* xT_l = (unsigned short*)(wsb + ((size_t)108 << 20)); // 4 MB bf16 (B,D,T) lo

    k_input_ln<<<B_ * T_, 256, 0, stream>>>(inputs, in_w, in_b, x);
    for (int l = 0; l < 3; l++) {
        k_gemm<0><<<dim3(4, 16, 32), 256, 0, stream>>>(x, encoder, xs, 256, 256);
        k_rope_bf16<<<4096, 256, 0, stream>>>(xs, qr_h, qr_l);
        k_xT<<<dim3(16, 4, 8), 256, 0, stream>>>(x, xT_h, xT_l);
        k_attn_mfma<<<256, 512, 0, stream>>>(qr_h, qr_l, xT_h, xT_l, ykv);
        k_gemm<1><<<dim3(4, 16, 32), 256, 0, stream>>>(ykv, encoder_v, xs, 256, 256);
        k_gemm<2><<<dim3(4, 128, 1), 256, 0, stream>>>(xs, decoder, ymlp, 1024, 1024);
        k_resid_ln<<<B_ * T_, 256, 0, stream>>>(x, ymlp);
    }
    k_logits<<<B_ * T_, 256, 0, stream>>>(x, out_w, out_b, (float*)d_out);
}

// Round 6
// 1255.355 us; speedup vs baseline: 2.0240x; 1.2687x over previous
//
#include <hip/hip_runtime.h>
#include <hip/hip_bf16.h>
#include <math.h>

#define B_ 8
#define T_ 1024
#define D_ 256
#define NH_ 4
#define N_ 256
#define EPS_ 1e-5f

typedef __attribute__((ext_vector_type(8))) short short8_t;
typedef __attribute__((ext_vector_type(4))) float floatx4;

__device__ inline unsigned short f2bf(float f) {
    unsigned u = __builtin_bit_cast(unsigned, f);
    u += 0x7FFFu + ((u >> 16) & 1u);          // round-to-nearest-even
    return (unsigned short)(u >> 16);
}
__device__ inline float bf2f(unsigned short h) {
    return __builtin_bit_cast(float, (unsigned)h << 16);
}

// ---------- helpers ----------
__device__ inline float2 block_stats_256(float v, float* red) {
    float s1 = v, s2 = v * v;
    #pragma unroll
    for (int o = 32; o > 0; o >>= 1) { s1 += __shfl_down(s1, o); s2 += __shfl_down(s2, o); }
    int wave = threadIdx.x >> 6, lane = threadIdx.x & 63;
    __syncthreads();
    if (lane == 0) { red[wave] = s1; red[4 + wave] = s2; }
    __syncthreads();
    float S1 = red[0] + red[1] + red[2] + red[3];
    float S2 = red[4] + red[5] + red[6] + red[7];
    float mean = S1 * (1.f / 256.f);
    float var  = S2 * (1.f / 256.f) - mean * mean;
    return make_float2(mean, var);
}

// ---------- weight transpose + split:  in (R x C fp32, per head) -> outT hi/lo (C x R bf16) ----------
__global__ __launch_bounds__(256) void k_wT(
    const float* __restrict__ in, unsigned short* __restrict__ outh,
    unsigned short* __restrict__ outl, int R, int C)
{
    __shared__ float tile[64][65];
    int c0 = blockIdx.x * 64, r0 = blockIdx.y * 64, h = blockIdx.z;
    in += (size_t)h * R * C;
    for (int i = threadIdx.x; i < 4096; i += 256) {
        int r = i >> 6, c = i & 63;
        tile[r][c] = in[(size_t)(r0 + r) * C + c0 + c];
    }
    __syncthreads();
    for (int i = threadIdx.x; i < 4096; i += 256) {
        int c = i >> 6, r = i & 63;
        float v = tile[r][c];
        unsigned short hb = f2bf(v);
        size_t o = (size_t)(h * C + c0 + c) * R + r0 + r;
        outh[o] = hb;
        outl[o] = f2bf(v - bf2f(hb));
    }
}

// ---------- input projection + LN (+ bf16 hi/lo split of x) ----------
__global__ __launch_bounds__(256) void k_input_ln(
    const float* __restrict__ inputs, const float* __restrict__ in_w,
    const float* __restrict__ in_b, float* __restrict__ x,
    unsigned short* __restrict__ xh, unsigned short* __restrict__ xl)
{
    __shared__ float red[8];
    int row = blockIdx.x;
    int d = threadIdx.x;
    float v = inputs[row] * in_w[d] + in_b[d];
    float2 mv = block_stats_256(v, red);
    float o = (v - mv.x) * rsqrtf(mv.y + EPS_);
    size_t idx = (size_t)row * D_ + d;
    x[idx] = o;
    unsigned short hb = f2bf(o);
    xh[idx] = hb;
    xl[idx] = f2bf(o - bf2f(hb));
}

// ---------- split-bf16 MFMA GEMM:  C = A[M x K] @ W[K x N]  (WT: rows=n, cols=k) ----------
// 128x128 tile, 4 waves, wave = 64x64.  3-term split: Ah*Wh + Ah*Wl + Al*Wh.
// MODE 0 encoder : A=x (8192x256),  out xs hi/lo = split(relu(v)), pitch 1024
// MODE 1 enc_v   : A=ykv per bh (1024x256), out xy = split(xs * relu(v)), pitch 1024
// MODE 2 decoder : A=xy (8192x1024), out ymlp fp32, pitch 256
#define PG 40   // LDS pitch (32 + 8)
template<int MODE>
__global__ __launch_bounds__(256, 1) void k_gemm_mfma(
    const unsigned short* __restrict__ Ah, const unsigned short* __restrict__ Al,
    const unsigned short* __restrict__ Wh, const unsigned short* __restrict__ Wl,
    const unsigned short* __restrict__ xsh, const unsigned short* __restrict__ xsl,
    unsigned short* __restrict__ outh, unsigned short* __restrict__ outl,
    float* __restrict__ outf)
{
    constexpr int K = (MODE == 2) ? 1024 : 256;
    __shared__ unsigned short As_h[128 * PG], As_l[128 * PG];
    __shared__ unsigned short Ws_h[128 * PG], Ws_l[128 * PG];
    int tid = threadIdx.x;
    int w = tid >> 6, lane = tid & 63, quad = lane >> 4, l16 = lane & 15;
    int wm = w >> 1, wn = w & 1;
    int m0 = blockIdx.y * 128, n0x = blockIdx.x * 128;
    size_t a_row0, w_row0, out_row0;
    int col0;
    if (MODE == 1) {
        int bh = blockIdx.z;
        a_row0 = (size_t)bh * 1024 + m0;
        w_row0 = (size_t)((bh & 3) * 256 + n0x);
        out_row0 = (size_t)(bh >> 2) * 1024 + m0;
        col0 = (bh & 3) * 256 + n0x;
    } else {
        a_row0 = m0; w_row0 = n0x; out_row0 = m0; col0 = n0x;
    }
    floatx4 acc[4][4];
    #pragma unroll
    for (int mt = 0; mt < 4; mt++)
        #pragma unroll
        for (int nt = 0; nt < 4; nt++)
            acc[mt][nt] = (floatx4){0.f, 0.f, 0.f, 0.f};

    for (int k0 = 0; k0 < K; k0 += 32) {
        #pragma unroll
        for (int it = 0; it < 2; it++) {
            int fl = tid + it * 256;
            int row = fl >> 2, ch = fl & 3;
            size_t ga = (a_row0 + row) * (size_t)K + k0 + ch * 8;
            size_t gw = (w_row0 + row) * (size_t)K + k0 + ch * 8;
            *(short8_t*)&As_h[row * PG + ch * 8] = *(const short8_t*)(Ah + ga);
            *(short8_t*)&As_l[row * PG + ch * 8] = *(const short8_t*)(Al + ga);
            *(short8_t*)&Ws_h[row * PG + ch * 8] = *(const short8_t*)(Wh + gw);
            *(short8_t*)&Ws_l[row * PG + ch * 8] = *(const short8_t*)(Wl + gw);
        }
        __syncthreads();
        short8_t afh[4], afl[4], bfh[4], bfl[4];
        #pragma unroll
        for (int mt = 0; mt < 4; mt++) {
            afh[mt] = *(const short8_t*)&As_h[(wm * 64 + mt * 16 + l16) * PG + quad * 8];
            afl[mt] = *(const short8_t*)&As_l[(wm * 64 + mt * 16 + l16) * PG + quad * 8];
        }
        #pragma unroll
        for (int nt = 0; nt < 4; nt++) {
            bfh[nt] = *(const short8_t*)&Ws_h[(wn * 64 + nt * 16 + l16) * PG + quad * 8];
            bfl[nt] = *(const short8_t*)&Ws_l[(wn * 64 + nt * 16 + l16) * PG + quad * 8];
        }
        #pragma unroll
        for (int mt = 0; mt < 4; mt++)
            #pragma unroll
            for (int nt = 0; nt < 4; nt++) {
                acc[mt][nt] = __builtin_amdgcn_mfma_f32_16x16x32_bf16(afh[mt], bfh[nt], acc[mt][nt], 0, 0, 0);
                acc[mt][nt] = __builtin_amdgcn_mfma_f32_16x16x32_bf16(afh[mt], bfl[nt], acc[mt][nt], 0, 0, 0);
                acc[mt][nt] = __builtin_amdgcn_mfma_f32_16x16x32_bf16(afl[mt], bfh[nt], acc[mt][nt], 0, 0, 0);
            }
        __syncthreads();
    }

    #pragma unroll
    for (int mt = 0; mt < 4; mt++) {
        #pragma unroll
        for (int r = 0; r < 4; r++) {
            size_t grow = out_row0 + wm * 64 + mt * 16 + quad * 4 + r;
            #pragma unroll
            for (int nt = 0; nt < 4; nt++) {
                int gcol = col0 + wn * 64 + nt * 16 + l16;
                float v = acc[mt][nt][r];
                if (MODE == 0) {
                    v = fmaxf(v, 0.f);
                    size_t o = grow * 1024 + gcol;
                    unsigned short hb = f2bf(v);
                    outh[o] = hb;
                    outl[o] = f2bf(v - bf2f(hb));
                } else if (MODE == 1) {
                    float y = fmaxf(v, 0.f);
                    size_t o = grow * 1024 + gcol;
                    float xv = bf2f(xsh[o]) + bf2f(xsl[o]);
                    float p = xv * y;
                    unsigned short hb = f2bf(p);
                    outh[o] = hb;
                    outl[o] = f2bf(p - bf2f(hb));
                } else {
                    outf[grow * 256 + gcol] = v;
                }
            }
        }
    }
}

// ---------- rope: xs hi/lo (B,T,NH,N) -> qr hi/lo (B,NH,T,N) bf16 ----------
__global__ __launch_bounds__(256) void k_rope_bf16(
    const unsigned short* __restrict__ xsh, const unsigned short* __restrict__ xsl,
    unsigned short* __restrict__ qh, unsigned short* __restrict__ ql)
{
    int tid = blockIdx.x * 256 + threadIdx.x;   // 1M threads, 8 elems each
    int e0 = tid * 8;
    int n0 = e0 & 255;
    int t  = (e0 >> 8) & 1023;
    int bh = e0 >> 18;
    int h = bh & 3, b = bh >> 2;
    size_t src = (((size_t)(b * T_ + t) * NH_ + h) << 8) + n0;
    short8_t vh = *(const short8_t*)(xsh + src);
    short8_t vl = *(const short8_t*)(xsl + src);
    float v[8];
    #pragma unroll
    for (int i = 0; i < 8; i++)
        v[i] = bf2f((unsigned short)vh[i]) + bf2f((unsigned short)vl[i]);
    float cc[4], ss[4];
    int p0 = n0 >> 1;
    #pragma unroll
    for (int i = 0; i < 4; i++) {
        int p = p0 + i;
        int j = p & 63;
        int pos = (p < 64) ? (t & 31) : (t >> 5);
        float f = powf(10000.f, -(float)j * (1.f / 64.f));
        float ang = (float)pos * f;
        sincosf(ang, &ss[i], &cc[i]);
    }
    float r[8];
    r[0] = v[0] * cc[0] - v[1] * ss[0];
    r[1] = v[0] * ss[0] + v[1] * cc[0];
    r[2] = v[2] * cc[1] - v[3] * ss[1];
    r[3] = v[2] * ss[1] + v[3] * cc[1];
    r[4] = v[4] * cc[2] - v[5] * ss[2];
    r[5] = v[4] * ss[2] + v[5] * cc[2];
    r[6] = v[6] * cc[3] - v[7] * ss[3];
    r[7] = v[6] * ss[3] + v[7] * cc[3];
    short8_t oh, ol;
    #pragma unroll
    for (int i = 0; i < 8; i++) {
        unsigned short hbits = f2bf(r[i]);
        oh[i] = (short)hbits;
        ol[i] = (short)f2bf(r[i] - bf2f(hbits));
    }
    *(short8_t*)(qh + e0) = oh;
    *(short8_t*)(ql + e0) = ol;
}

// ---------- x (B,T,D) fp32 -> xT hi/lo (B,D,T) bf16 ----------
__global__ __launch_bounds__(256) void k_xT(const float* __restrict__ x,
                                            unsigned short* __restrict__ xTh,
                                            unsigned short* __restrict__ xTl)
{
    __shared__ float tile[64][65];
    int t0 = blockIdx.x * 64, d0 = blockIdx.y * 64, b = blockIdx.z;
    const float* src = x + ((size_t)b * T_ + t0) * D_ + d0;
    for (int i = threadIdx.x; i < 1024; i += 256) {
        int r = i >> 4, c = i & 15;
        float4 v = *(const float4*)(src + (size_t)r * D_ + c * 4);
        tile[r][c * 4 + 0] = v.x;
        tile[r][c * 4 + 1] = v.y;
        tile[r][c * 4 + 2] = v.z;
        tile[r][c * 4 + 3] = v.w;
    }
    __syncthreads();
    size_t dbase = ((size_t)b * D_ + d0) * T_ + t0;
    for (int i = threadIdx.x; i < 1024; i += 256) {
        int d = i >> 4, c = i & 15;
        ushort4 oh, ol;
        float v0 = tile[c * 4 + 0][d], v1 = tile[c * 4 + 1][d];
        float v2 = tile[c * 4 + 2][d], v3 = tile[c * 4 + 3][d];
        oh.x = f2bf(v0); ol.x = f2bf(v0 - bf2f(oh.x));
        oh.y = f2bf(v1); ol.y = f2bf(v1 - bf2f(oh.y));
        oh.z = f2bf(v2); ol.z = f2bf(v2 - bf2f(oh.z));
        oh.w = f2bf(v3); ol.w = f2bf(v3 - bf2f(oh.w));
        size_t o = dbase + (size_t)d * T_ + c * 4;
        *(ushort4*)(xTh + o) = oh;
        *(ushort4*)(xTl + o) = ol;
    }
}

// ---------- fused split-bf16 MFMA flash attention + /l + LayerNorm ----------
// block = (b,h, 128-query tile), 8 waves (2 waves/SIMD, 1 block/CU).
// QK: wave w owns q rows w*16..+16.  PV: wave w owns q-half (w>>2), d (w&3)*64.
// Epilogue writes ykv as bf16 hi/lo (A-operand of the next GEMM).
#define PK 264   // K_lds pitch: 256+8
#define PP 72    // P_lds pitch: 64+8

__global__ __launch_bounds__(512, 1) void k_attn_mfma(
    const unsigned short* __restrict__ qr_h, const unsigned short* __restrict__ qr_l,
    const unsigned short* __restrict__ xT_h, const unsigned short* __restrict__ xT_l,
    unsigned short* __restrict__ ykvh, unsigned short* __restrict__ ykvl)
{
    __shared__ unsigned short K_h[64 * PK];      // 33792 B
    __shared__ unsigned short K_l[64 * PK];      // 33792 B
    __shared__ unsigned short P_h[128 * PP];     // 18432 B
    __shared__ unsigned short P_l[128 * PP];     // 18432 B
    __shared__ float alpha_lds[128];
    __shared__ float linv_lds[128];
    __shared__ float stat_lds[2][128][4];
    __shared__ float ab_lds[2][128];

    int tid = threadIdx.x;
    int w = tid >> 6, lane = tid & 63, quad = lane >> 4, l16 = lane & 15;
    int h2 = w >> 2, qw = w & 3;                 // PV role
    int gid = blockIdx.x;
    int tile = gid & 7, bh = gid >> 3, b = bh >> 2;
    int t0q = tile * 128;
    const unsigned short* qhb = qr_h + (size_t)bh * T_ * N_;
    const unsigned short* qlb = qr_l + (size_t)bh * T_ * N_;
    const unsigned short* xhb = xT_h + (size_t)b * D_ * T_;
    const unsigned short* xlb = xT_l + (size_t)b * D_ * T_;

    // Q A-frags straight from global (once; L2-hot)
    short8_t qfh[8], qfl[8];
    #pragma unroll
    for (int kc = 0; kc < 8; kc++) {
        size_t o = (size_t)(t0q + w * 16 + l16) * N_ + quad * 8 + kc * 32;
        qfh[kc] = *(const short8_t*)(qhb + o);
        qfl[kc] = *(const short8_t*)(qlb + o);
    }

    // prefetch K tile 0 into registers
    short8_t pre_h[4], pre_l[4];
    #pragma unroll
    for (int it = 0; it < 4; it++) {
        int fl = tid + it * 512;
        int row = fl >> 5, c16 = fl & 31;
        pre_h[it] = *(const short8_t*)(qhb + (size_t)row * N_ + c16 * 8);
        pre_l[it] = *(const short8_t*)(qlb + (size_t)row * N_ + c16 * 8);
    }

    floatx4 O[4][4];
    #pragma unroll
    for (int mt = 0; mt < 4; mt++)
        #pragma unroll
        for (int tn = 0; tn < 4; tn++)
            O[mt][tn] = (floatx4){0.f, 0.f, 0.f, 0.f};
    float Mst[4] = {-1e30f, -1e30f, -1e30f, -1e30f};
    float lst[4] = {0.f, 0.f, 0.f, 0.f};
    const float scale = 0.0625f;   // 1/sqrt(256)

    for (int j = 0; j < 16; j++) {
        // commit prefetched K tile to LDS
        #pragma unroll
        for (int it = 0; it < 4; it++) {
            int fl = tid + it * 512;
            int row = fl >> 5, c16 = fl & 31;
            *(short8_t*)&K_h[row * PK + c16 * 8] = pre_h[it];
            *(short8_t*)&K_l[row * PK + c16 * 8] = pre_l[it];
        }
        __syncthreads();
        // issue prefetch for next tile (overlaps with QK+softmax+PV)
        if (j < 15) {
            #pragma unroll
            for (int it = 0; it < 4; it++) {
                int fl = tid + it * 512;
                int row = fl >> 5, c16 = fl & 31;
                pre_h[it] = *(const short8_t*)(qhb + (size_t)((j + 1) * 64 + row) * N_ + c16 * 8);
                pre_l[it] = *(const short8_t*)(qlb + (size_t)((j + 1) * 64 + row) * N_ + c16 * 8);
            }
        }

        // QK^T, split 3-term
        floatx4 sc[4];
        #pragma unroll
        for (int ct = 0; ct < 4; ct++) {
            floatx4 acc = (floatx4){0.f, 0.f, 0.f, 0.f};
            #pragma unroll
            for (int kc = 0; kc < 8; kc++) {
                short8_t bkh = *(const short8_t*)&K_h[(ct * 16 + l16) * PK + quad * 8 + kc * 32];
                short8_t bkl = *(const short8_t*)&K_l[(ct * 16 + l16) * PK + quad * 8 + kc * 32];
                acc = __builtin_amdgcn_mfma_f32_16x16x32_bf16(qfh[kc], bkh, acc, 0, 0, 0);
                acc = __builtin_amdgcn_mfma_f32_16x16x32_bf16(qfh[kc], bkl, acc, 0, 0, 0);
                acc = __builtin_amdgcn_mfma_f32_16x16x32_bf16(qfl[kc], bkh, acc, 0, 0, 0);
            }
            sc[ct] = acc;
        }

        // online softmax per row (row = w*16 + quad*4 + r)
        float al[4];
        #pragma unroll
        for (int r = 0; r < 4; r++) {
            float m = fmaxf(fmaxf(sc[0][r], sc[1][r]), fmaxf(sc[2][r], sc[3][r])) * scale;
            #pragma unroll
            for (int o = 1; o < 16; o <<= 1) m = fmaxf(m, __shfl_xor(m, o));
            float Mn = fmaxf(Mst[r], m);
            float alpha = __expf(Mst[r] - Mn);
            Mst[r] = Mn;
            int row = w * 16 + quad * 4 + r;
            float rsum = 0.f;
            #pragma unroll
            for (int ct = 0; ct < 4; ct++) {
                float p = __expf(sc[ct][r] * scale - Mn);
                rsum += p;
                unsigned short ph = f2bf(p);
                P_h[row * PP + ct * 16 + l16] = ph;
                P_l[row * PP + ct * 16 + l16] = f2bf(p - bf2f(ph));
            }
            #pragma unroll
            for (int o = 1; o < 16; o <<= 1) rsum += __shfl_xor(rsum, o);
            lst[r] = lst[r] * alpha + rsum;
            al[r] = alpha;
        }
        if (l16 == 0) {
            #pragma unroll
            for (int r = 0; r < 4; r++) alpha_lds[w * 16 + quad * 4 + r] = al[r];
        }
        __syncthreads();

        // PV, split 3-term: wave w owns q-half h2, d range qw*64..+64
        #pragma unroll
        for (int mt = 0; mt < 4; mt++) {
            float af0 = alpha_lds[h2 * 64 + mt * 16 + quad * 4 + 0];
            float af1 = alpha_lds[h2 * 64 + mt * 16 + quad * 4 + 1];
            float af2 = alpha_lds[h2 * 64 + mt * 16 + quad * 4 + 2];
            float af3 = alpha_lds[h2 * 64 + mt * 16 + quad * 4 + 3];
            #pragma unroll
            for (int tn = 0; tn < 4; tn++) {
                O[mt][tn][0] *= af0; O[mt][tn][1] *= af1;
                O[mt][tn][2] *= af2; O[mt][tn][3] *= af3;
            }
        }
        short8_t vbh[4][2], vbl[4][2];
        #pragma unroll
        for (int tn = 0; tn < 4; tn++)
            #pragma unroll
            for (int kc = 0; kc < 2; kc++) {
                size_t o = (size_t)(qw * 64 + tn * 16 + l16) * T_ + j * 64 + quad * 8 + kc * 32;
                vbh[tn][kc] = *(const short8_t*)(xhb + o);
                vbl[tn][kc] = *(const short8_t*)(xlb + o);
            }
        #pragma unroll
        for (int mt = 0; mt < 4; mt++) {
            int prow = h2 * 64 + mt * 16 + l16;
            short8_t pa0h = *(const short8_t*)&P_h[prow * PP + quad * 8];
            short8_t pa1h = *(const short8_t*)&P_h[prow * PP + quad * 8 + 32];
            short8_t pa0l = *(const short8_t*)&P_l[prow * PP + quad * 8];
            short8_t pa1l = *(const short8_t*)&P_l[prow * PP + quad * 8 + 32];
            #pragma unroll
            for (int tn = 0; tn < 4; tn++) {
                O[mt][tn] = __builtin_amdgcn_mfma_f32_16x16x32_bf16(pa0h, vbh[tn][0], O[mt][tn], 0, 0, 0);
                O[mt][tn] = __builtin_amdgcn_mfma_f32_16x16x32_bf16(pa1h, vbh[tn][1], O[mt][tn], 0, 0, 0);
                O[mt][tn] = __builtin_amdgcn_mfma_f32_16x16x32_bf16(pa0h, vbl[tn][0], O[mt][tn], 0, 0, 0);
                O[mt][tn] = __builtin_amdgcn_mfma_f32_16x16x32_bf16(pa1h, vbl[tn][1], O[mt][tn], 0, 0, 0);
                O[mt][tn] = __builtin_amdgcn_mfma_f32_16x16x32_bf16(pa0l, vbh[tn][0], O[mt][tn], 0, 0, 0);
                O[mt][tn] = __builtin_amdgcn_mfma_f32_16x16x32_bf16(pa1l, vbh[tn][1], O[mt][tn], 0, 0, 0);
            }
        }
        __syncthreads();
    }

    // epilogue: yKV = LN_d(O / l), written as bf16 hi/lo
    if (l16 == 0) {
        #pragma unroll
        for (int r = 0; r < 4; r++) linv_lds[w * 16 + quad * 4 + r] = 1.f / lst[r];
    }
    #pragma unroll
    for (int mt = 0; mt < 4; mt++) {
        #pragma unroll
        for (int r = 0; r < 4; r++) {
            float a0 = O[mt][0][r], a1 = O[mt][1][r], a2 = O[mt][2][r], a3 = O[mt][3][r];
            float s1 = a0 + a1 + a2 + a3;
            float s2 = a0 * a0 + a1 * a1 + a2 * a2 + a3 * a3;
            #pragma unroll
            for (int o = 1; o < 16; o <<= 1) { s1 += __shfl_xor(s1, o); s2 += __shfl_xor(s2, o); }
            if (l16 == 0) {
                stat_lds[0][h2 * 64 + mt * 16 + quad * 4 + r][qw] = s1;
                stat_lds[1][h2 * 64 + mt * 16 + quad * 4 + r][qw] = s2;
            }
        }
    }
    __syncthreads();
    if (tid < 128) {
        float li = linv_lds[tid];
        float S1 = stat_lds[0][tid][0] + stat_lds[0][tid][1] + stat_lds[0][tid][2] + stat_lds[0][tid][3];
        float S2 = stat_lds[1][tid][0] + stat_lds[1][tid][1] + stat_lds[1][tid][2] + stat_lds[1][tid][3];
        float mean = S1 * li * (1.f / 256.f);
        float e2   = S2 * li * li * (1.f / 256.f);
        float var  = e2 - mean * mean;
        float rs = rsqrtf(var + EPS_);
        ab_lds[0][tid] = li * rs;
        ab_lds[1][tid] = mean * rs;
    }
    __syncthreads();
    size_t obase = ((size_t)bh * T_ + t0q) * D_;
    #pragma unroll
    for (int mt = 0; mt < 4; mt++) {
        #pragma unroll
        for (int r = 0; r < 4; r++) {
            int row = h2 * 64 + mt * 16 + quad * 4 + r;
            float a = ab_lds[0][row], bb = ab_lds[1][row];
            #pragma unroll
            for (int tn = 0; tn < 4; tn++) {
                float v = O[mt][tn][r] * a - bb;
                size_t o = obase + (size_t)row * D_ + qw * 64 + tn * 16 + l16;
                unsigned short hb = f2bf(v);
                ykvh[o] = hb;
                ykvl[o] = f2bf(v - bf2f(hb));
            }
        }
    }
}

// ---------- residual + double LN (+ bf16 hi/lo split of x) ----------
__global__ __launch_bounds__(256) void k_resid_ln(float* __restrict__ x,
                                                  const float* __restrict__ ymlp,
                                                  unsigned short* __restrict__ xh,
                                                  unsigned short* __restrict__ xl)
{
    __shared__ float red[8];
    int row = blockIdx.x, d = threadIdx.x;
    size_t o = (size_t)row * D_ + d;
    float y = ymlp[o];
    float2 mv1 = block_stats_256(y, red);
    float v = x[o] + (y - mv1.x) * rsqrtf(mv1.y + EPS_);
    float2 mv2 = block_stats_256(v, red);
    float out = (v - mv2.x) * rsqrtf(mv2.y + EPS_);
    x[o] = out;
    unsigned short hb = f2bf(out);
    xh[o] = hb;
    xl[o] = f2bf(out - bf2f(hb));
}

// ---------- logits ----------
__global__ __launch_bounds__(256) void k_logits(
    const float* __restrict__ x, const float* __restrict__ out_w,
    const float* __restrict__ out_b, float* __restrict__ out)
{
    __shared__ float red[4];
    int row = blockIdx.x, d = threadIdx.x;
    float v = x[(size_t)row * D_ + d] * out_w[d];
    #pragma unroll
    for (int o = 32; o > 0; o >>= 1) v += __shfl_down(v, o);
    int wave = d >> 6, lane = d & 63;
    if (lane == 0) red[wave] = v;
    __syncthreads();
    if (d == 0) out[row] = red[0] + red[1] + red[2] + red[3] + out_b[0];
}

extern "C" void kernel_launch(void* const* d_in, const int* in_sizes, int n_in,
                              void* d_out, int out_size, void* d_ws, size_t ws_size,
                              hipStream_t stream)
{
    (void)in_sizes; (void)n_in; (void)out_size;
    if (ws_size < ((size_t)115 << 20)) return;

    const float* inputs    = (const float*)d_in[0];
    const float* in_w      = (const float*)d_in[1];
    const float* in_b      = (const float*)d_in[2];
    const float* encoder   = (const float*)d_in[3];
    const float* encoder_v = (const float*)d_in[4];
    const float* decoder   = (const float*)d_in[5];
    const float* out_w     = (const float*)d_in[6];
    const float* out_b     = (const float*)d_in[7];

    char* wsb = (char*)d_ws;
    float* x             = (float*)(wsb);                                 //  8 MB fp32 (B,T,D)
    unsigned short* x_h  = (unsigned short*)(wsb + ((size_t)8  << 20));   //  4 MB bf16 (B,T,D) hi
    unsigned short* x_l  = (unsigned short*)(wsb + ((size_t)12 << 20));   //  4 MB lo
    unsigned short* xT_h = x_h;                                           //  ALIAS: xT (B,D,T) lives
    unsigned short* xT_l = x_l;                                           //  here between k_xT & attn
    unsigned short* xs_h = (unsigned short*)(wsb + ((size_t)16 << 20));   // 16 MB (B,T,NH*N) hi
    unsigned short* xs_l = (unsigned short*)(wsb + ((size_t)32 << 20));   // 16 MB lo
    float* ymlp          = (float*)(wsb + ((size_t)16 << 20));            //  8 MB fp32, ALIASES xs_h
                                                                          //  (xs dead after gemm<1>;
                                                                          //   gemm<0> rewrites next layer)
    unsigned short* qr_h = (unsigned short*)(wsb + ((size_t)48 << 20));   // 16 MB (B,NH,T,N) hi
    unsigned short* qr_l = (unsigned short*)(wsb + ((size_t)64 << 20));   // 16 MB lo
    unsigned short* xy_h = qr_h;                                          //  ALIAS: xy after attn
    unsigned short* xy_l = qr_l;
    unsigned short* ykv_h = (unsigned short*)(wsb + ((size_t)80 << 20));  // 16 MB (B,NH,T,D) hi
    unsigned short* ykv_l = (unsigned short*)(wsb + ((size_t)96 << 20));  // 16 MB lo
    char* wbase = wsb + ((size_t)112 << 20);                              //  3 MB weights
    unsigned short* encT_h = (unsigned short*)(wbase);                    // 0.5 MB (NH*N, D)
    unsigned short* encT_l = (unsigned short*)(wbase + 0x80000);
    unsigned short* evT_h  = (unsigned short*)(wbase + 2 * 0x80000);
    unsigned short* evT_l  = (unsigned short*)(wbase + 3 * 0x80000);
    unsigned short* decT_h = (unsigned short*)(wbase + 4 * 0x80000);      // (D, NH*N)
    unsigned short* decT_l = (unsigned short*)(wbase + 5 * 0x80000);

    // weight transpose+split (runs every call; tiny)
    k_wT<<<dim3(4, 4, 4), 256, 0, stream>>>(encoder,   encT_h, encT_l, 256, 256);
    k_wT<<<dim3(4, 4, 4), 256, 0, stream>>>(encoder_v, evT_h,  evT_l,  256, 256);
    k_wT<<<dim3(4, 16, 1), 256, 0, stream>>>(decoder,  decT_h, decT_l, 1024, 256);

    k_input_ln<<<B_ * T_, 256, 0, stream>>>(inputs, in_w, in_b, x, x_h, x_l);
    for (int l = 0; l < 3; l++) {
        k_gemm_mfma<0><<<dim3(8, 64, 1), 256, 0, stream>>>(
            x_h, x_l, encT_h, encT_l, nullptr, nullptr, xs_h, xs_l, nullptr);
        k_rope_bf16<<<4096, 256, 0, stream>>>(xs_h, xs_l, qr_h, qr_l);
        k_xT<<<dim3(16, 4, 8), 256, 0, stream>>>(x, xT_h, xT_l);   // overwrites x_h/x_l region
        k_attn_mfma<<<256, 512, 0, stream>>>(qr_h, qr_l, xT_h, xT_l, ykv_h, ykv_l);
        k_gemm_mfma<1><<<dim3(2, 8, 32), 256, 0, stream>>>(
            ykv_h, ykv_l, evT_h, evT_l, xs_h, xs_l, xy_h, xy_l, nullptr);
        k_gemm_mfma<2><<<dim3(2, 64, 1), 256, 0, stream>>>(
            xy_h, xy_l, decT_h, decT_l, nullptr, nullptr, nullptr, nullptr, ymlp);
        k_resid_ln<<<B_ * T_, 256, 0, stream>>>(x, ymlp, x_h, x_l);  // regenerates x_h/x_l
    }
    k_logits<<<B_ * T_, 256, 0, stream>>>(x, out_w, out_b, (float*)d_out);
}

// Round 7
// 1073.039 us; speedup vs baseline: 2.3679x; 1.1699x over previous
//
#include <hip/hip_runtime.h>
#include <hip/hip_bf16.h>
#include <math.h>

#define B_ 8
#define T_ 1024
#define D_ 256
#define NH_ 4
#define N_ 256
#define EPS_ 1e-5f

typedef __attribute__((ext_vector_type(8))) short short8_t;
typedef __attribute__((ext_vector_type(4))) float floatx4;

__device__ inline unsigned short f2bf(float f) {
    unsigned u = __builtin_bit_cast(unsigned, f);
    u += 0x7FFFu + ((u >> 16) & 1u);          // round-to-nearest-even
    return (unsigned short)(u >> 16);
}
__device__ inline float bf2f(unsigned short h) {
    return __builtin_bit_cast(float, (unsigned)h << 16);
}

// async global->LDS, 16 B per lane; lds base wave-uniform, HW adds lane*16
__device__ inline void gload_lds16(const unsigned short* g, unsigned short* l) {
    __builtin_amdgcn_global_load_lds(
        (const __attribute__((address_space(1))) unsigned int*)g,
        (__attribute__((address_space(3))) unsigned int*)l, 16, 0, 0);
}

// ---------- helpers ----------
__device__ inline float2 block_stats_256(float v, float* red) {
    float s1 = v, s2 = v * v;
    #pragma unroll
    for (int o = 32; o > 0; o >>= 1) { s1 += __shfl_down(s1, o); s2 += __shfl_down(s2, o); }
    int wave = threadIdx.x >> 6, lane = threadIdx.x & 63;
    __syncthreads();
    if (lane == 0) { red[wave] = s1; red[4 + wave] = s2; }
    __syncthreads();
    float S1 = red[0] + red[1] + red[2] + red[3];
    float S2 = red[4] + red[5] + red[6] + red[7];
    float mean = S1 * (1.f / 256.f);
    float var  = S2 * (1.f / 256.f) - mean * mean;
    return make_float2(mean, var);
}

// ---------- weight transpose + split ----------
__global__ __launch_bounds__(256) void k_wT(
    const float* __restrict__ in, unsigned short* __restrict__ outh,
    unsigned short* __restrict__ outl, int R, int C)
{
    __shared__ float tile[64][65];
    int c0 = blockIdx.x * 64, r0 = blockIdx.y * 64, h = blockIdx.z;
    in += (size_t)h * R * C;
    for (int i = threadIdx.x; i < 4096; i += 256) {
        int r = i >> 6, c = i & 63;
        tile[r][c] = in[(size_t)(r0 + r) * C + c0 + c];
    }
    __syncthreads();
    for (int i = threadIdx.x; i < 4096; i += 256) {
        int c = i >> 6, r = i & 63;
        float v = tile[r][c];
        unsigned short hb = f2bf(v);
        size_t o = (size_t)(h * C + c0 + c) * R + r0 + r;
        outh[o] = hb;
        outl[o] = f2bf(v - bf2f(hb));
    }
}

// ---------- input projection + LN (+ bf16 hi/lo split of x) ----------
__global__ __launch_bounds__(256) void k_input_ln(
    const float* __restrict__ inputs, const float* __restrict__ in_w,
    const float* __restrict__ in_b, float* __restrict__ x,
    unsigned short* __restrict__ xh, unsigned short* __restrict__ xl)
{
    __shared__ float red[8];
    int row = blockIdx.x;
    int d = threadIdx.x;
    float v = inputs[row] * in_w[d] + in_b[d];
    float2 mv = block_stats_256(v, red);
    float o = (v - mv.x) * rsqrtf(mv.y + EPS_);
    size_t idx = (size_t)row * D_ + d;
    x[idx] = o;
    unsigned short hb = f2bf(o);
    xh[idx] = hb;
    xl[idx] = f2bf(o - bf2f(hb));
}

// ---------- split-bf16 MFMA GEMM (unchanged from round 6) ----------
#define PG 40   // LDS pitch (32 + 8)
template<int MODE>
__global__ __launch_bounds__(256, 1) void k_gemm_mfma(
    const unsigned short* __restrict__ Ah, const unsigned short* __restrict__ Al,
    const unsigned short* __restrict__ Wh, const unsigned short* __restrict__ Wl,
    const unsigned short* __restrict__ xsh, const unsigned short* __restrict__ xsl,
    unsigned short* __restrict__ outh, unsigned short* __restrict__ outl,
    float* __restrict__ outf)
{
    constexpr int K = (MODE == 2) ? 1024 : 256;
    __shared__ unsigned short As_h[128 * PG], As_l[128 * PG];
    __shared__ unsigned short Ws_h[128 * PG], Ws_l[128 * PG];
    int tid = threadIdx.x;
    int w = tid >> 6, lane = tid & 63, quad = lane >> 4, l16 = lane & 15;
    int wm = w >> 1, wn = w & 1;
    int m0 = blockIdx.y * 128, n0x = blockIdx.x * 128;
    size_t a_row0, w_row0, out_row0;
    int col0;
    if (MODE == 1) {
        int bh = blockIdx.z;
        a_row0 = (size_t)bh * 1024 + m0;
        w_row0 = (size_t)((bh & 3) * 256 + n0x);
        out_row0 = (size_t)(bh >> 2) * 1024 + m0;
        col0 = (bh & 3) * 256 + n0x;
    } else {
        a_row0 = m0; w_row0 = n0x; out_row0 = m0; col0 = n0x;
    }
    floatx4 acc[4][4];
    #pragma unroll
    for (int mt = 0; mt < 4; mt++)
        #pragma unroll
        for (int nt = 0; nt < 4; nt++)
            acc[mt][nt] = (floatx4){0.f, 0.f, 0.f, 0.f};

    for (int k0 = 0; k0 < K; k0 += 32) {
        #pragma unroll
        for (int it = 0; it < 2; it++) {
            int fl = tid + it * 256;
            int row = fl >> 2, ch = fl & 3;
            size_t ga = (a_row0 + row) * (size_t)K + k0 + ch * 8;
            size_t gw = (w_row0 + row) * (size_t)K + k0 + ch * 8;
            *(short8_t*)&As_h[row * PG + ch * 8] = *(const short8_t*)(Ah + ga);
            *(short8_t*)&As_l[row * PG + ch * 8] = *(const short8_t*)(Al + ga);
            *(short8_t*)&Ws_h[row * PG + ch * 8] = *(const short8_t*)(Wh + gw);
            *(short8_t*)&Ws_l[row * PG + ch * 8] = *(const short8_t*)(Wl + gw);
        }
        __syncthreads();
        short8_t afh[4], afl[4], bfh[4], bfl[4];
        #pragma unroll
        for (int mt = 0; mt < 4; mt++) {
            afh[mt] = *(const short8_t*)&As_h[(wm * 64 + mt * 16 + l16) * PG + quad * 8];
            afl[mt] = *(const short8_t*)&As_l[(wm * 64 + mt * 16 + l16) * PG + quad * 8];
        }
        #pragma unroll
        for (int nt = 0; nt < 4; nt++) {
            bfh[nt] = *(const short8_t*)&Ws_h[(wn * 64 + nt * 16 + l16) * PG + quad * 8];
            bfl[nt] = *(const short8_t*)&Ws_l[(wn * 64 + nt * 16 + l16) * PG + quad * 8];
        }
        #pragma unroll
        for (int mt = 0; mt < 4; mt++)
            #pragma unroll
            for (int nt = 0; nt < 4; nt++) {
                acc[mt][nt] = __builtin_amdgcn_mfma_f32_16x16x32_bf16(afh[mt], bfh[nt], acc[mt][nt], 0, 0, 0);
                acc[mt][nt] = __builtin_amdgcn_mfma_f32_16x16x32_bf16(afh[mt], bfl[nt], acc[mt][nt], 0, 0, 0);
                acc[mt][nt] = __builtin_amdgcn_mfma_f32_16x16x32_bf16(afl[mt], bfh[nt], acc[mt][nt], 0, 0, 0);
            }
        __syncthreads();
    }

    #pragma unroll
    for (int mt = 0; mt < 4; mt++) {
        #pragma unroll
        for (int r = 0; r < 4; r++) {
            size_t grow = out_row0 + wm * 64 + mt * 16 + quad * 4 + r;
            #pragma unroll
            for (int nt = 0; nt < 4; nt++) {
                int gcol = col0 + wn * 64 + nt * 16 + l16;
                float v = acc[mt][nt][r];
                if (MODE == 0) {
                    v = fmaxf(v, 0.f);
                    size_t o = grow * 1024 + gcol;
                    unsigned short hb = f2bf(v);
                    outh[o] = hb;
                    outl[o] = f2bf(v - bf2f(hb));
                } else if (MODE == 1) {
                    float y = fmaxf(v, 0.f);
                    size_t o = grow * 1024 + gcol;
                    float xv = bf2f(xsh[o]) + bf2f(xsl[o]);
                    float p = xv * y;
                    unsigned short hb = f2bf(p);
                    outh[o] = hb;
                    outl[o] = f2bf(p - bf2f(hb));
                } else {
                    outf[grow * 256 + gcol] = v;
                }
            }
        }
    }
}

// ---------- rope: xs hi/lo (B,T,NH,N) -> qr hi/lo (B,NH,T,N) bf16 ----------
__global__ __launch_bounds__(256) void k_rope_bf16(
    const unsigned short* __restrict__ xsh, const unsigned short* __restrict__ xsl,
    unsigned short* __restrict__ qh, unsigned short* __restrict__ ql)
{
    int tid = blockIdx.x * 256 + threadIdx.x;
    int e0 = tid * 8;
    int n0 = e0 & 255;
    int t  = (e0 >> 8) & 1023;
    int bh = e0 >> 18;
    int h = bh & 3, b = bh >> 2;
    size_t src = (((size_t)(b * T_ + t) * NH_ + h) << 8) + n0;
    short8_t vh = *(const short8_t*)(xsh + src);
    short8_t vl = *(const short8_t*)(xsl + src);
    float v[8];
    #pragma unroll
    for (int i = 0; i < 8; i++)
        v[i] = bf2f((unsigned short)vh[i]) + bf2f((unsigned short)vl[i]);
    float cc[4], ss[4];
    int p0 = n0 >> 1;
    #pragma unroll
    for (int i = 0; i < 4; i++) {
        int p = p0 + i;
        int j = p & 63;
        int pos = (p < 64) ? (t & 31) : (t >> 5);
        float f = powf(10000.f, -(float)j * (1.f / 64.f));
        float ang = (float)pos * f;
        sincosf(ang, &ss[i], &cc[i]);
    }
    float r[8];
    r[0] = v[0] * cc[0] - v[1] * ss[0];
    r[1] = v[0] * ss[0] + v[1] * cc[0];
    r[2] = v[2] * cc[1] - v[3] * ss[1];
    r[3] = v[2] * ss[1] + v[3] * cc[1];
    r[4] = v[4] * cc[2] - v[5] * ss[2];
    r[5] = v[4] * ss[2] + v[5] * cc[2];
    r[6] = v[6] * cc[3] - v[7] * ss[3];
    r[7] = v[6] * ss[3] + v[7] * cc[3];
    short8_t oh, ol;
    #pragma unroll
    for (int i = 0; i < 8; i++) {
        unsigned short hbits = f2bf(r[i]);
        oh[i] = (short)hbits;
        ol[i] = (short)f2bf(r[i] - bf2f(hbits));
    }
    *(short8_t*)(qh + e0) = oh;
    *(short8_t*)(ql + e0) = ol;
}

// ---------- x (B,T,D) fp32 -> xT hi/lo (B,D,T) bf16 ----------
__global__ __launch_bounds__(256) void k_xT(const float* __restrict__ x,
                                            unsigned short* __restrict__ xTh,
                                            unsigned short* __restrict__ xTl)
{
    __shared__ float tile[64][65];
    int t0 = blockIdx.x * 64, d0 = blockIdx.y * 64, b = blockIdx.z;
    const float* src = x + ((size_t)b * T_ + t0) * D_ + d0;
    for (int i = threadIdx.x; i < 1024; i += 256) {
        int r = i >> 4, c = i & 15;
        float4 v = *(const float4*)(src + (size_t)r * D_ + c * 4);
        tile[r][c * 4 + 0] = v.x;
        tile[r][c * 4 + 1] = v.y;
        tile[r][c * 4 + 2] = v.z;
        tile[r][c * 4 + 3] = v.w;
    }
    __syncthreads();
    size_t dbase = ((size_t)b * D_ + d0) * T_ + t0;
    for (int i = threadIdx.x; i < 1024; i += 256) {
        int d = i >> 4, c = i & 15;
        ushort4 oh, ol;
        float v0 = tile[c * 4 + 0][d], v1 = tile[c * 4 + 1][d];
        float v2 = tile[c * 4 + 2][d], v3 = tile[c * 4 + 3][d];
        oh.x = f2bf(v0); ol.x = f2bf(v0 - bf2f(oh.x));
        oh.y = f2bf(v1); ol.y = f2bf(v1 - bf2f(oh.y));
        oh.z = f2bf(v2); ol.z = f2bf(v2 - bf2f(oh.z));
        oh.w = f2bf(v3); ol.w = f2bf(v3 - bf2f(oh.w));
        size_t o = dbase + (size_t)d * T_ + c * 4;
        *(ushort4*)(xTh + o) = oh;
        *(ushort4*)(xTl + o) = ol;
    }
}

// ---------- fused split-bf16 MFMA flash attention + /l + LayerNorm ----------
// block = (b,h, 128-query tile), 8 waves. K staged via global_load_lds into
// FRAGMENT-ORDER LDS (slot(ct,kc) = 64 lanes x 16B contiguous): zero staging
// VGPRs (kills the round-6 spill) + conflict-free ds_read_b128.
// XCD swizzle: bh = gid&31 so one bh's 8 q-tiles share an XCD's L2.
#define PP 72    // P_lds pitch: 64+8

__global__ __launch_bounds__(512, 1) void k_attn_mfma(
    const unsigned short* __restrict__ qr_h, const unsigned short* __restrict__ qr_l,
    const unsigned short* __restrict__ xT_h, const unsigned short* __restrict__ xT_l,
    unsigned short* __restrict__ ykvh, unsigned short* __restrict__ ykvl)
{
    __shared__ unsigned short K_h[32 * 512];     // 32 KB, fragment order
    __shared__ unsigned short K_l[32 * 512];     // 32 KB
    __shared__ unsigned short P_h[128 * PP];     // 18432 B
    __shared__ unsigned short P_l[128 * PP];     // 18432 B
    __shared__ float alpha_lds[128];
    __shared__ float linv_lds[128];
    __shared__ float stat_lds[2][128][4];
    __shared__ float ab_lds[2][128];

    int tid = threadIdx.x;
    int w = tid >> 6, lane = tid & 63, quad = lane >> 4, l16 = lane & 15;
    int h2 = w >> 2, qw = w & 3;                 // PV role
    int gid = blockIdx.x;
    int bh = gid & 31, tile = gid >> 5, b = bh >> 2;   // XCD swizzle
    int t0q = tile * 128;
    const unsigned short* qhb = qr_h + (size_t)bh * T_ * N_;
    const unsigned short* qlb = qr_l + (size_t)bh * T_ * N_;
    const unsigned short* xhb = xT_h + (size_t)b * D_ * T_;
    const unsigned short* xlb = xT_l + (size_t)b * D_ * T_;

    // Q A-frags straight from global (once; L2-hot)
    short8_t qfh[8], qfl[8];
    #pragma unroll
    for (int kc = 0; kc < 8; kc++) {
        size_t o = (size_t)(t0q + w * 16 + l16) * N_ + quad * 8 + kc * 32;
        qfh[kc] = *(const short8_t*)(qhb + o);
        qfl[kc] = *(const short8_t*)(qlb + o);
    }

    floatx4 O[4][4];
    #pragma unroll
    for (int mt = 0; mt < 4; mt++)
        #pragma unroll
        for (int tn = 0; tn < 4; tn++)
            O[mt][tn] = (floatx4){0.f, 0.f, 0.f, 0.f};
    float Mst[4] = {-1e30f, -1e30f, -1e30f, -1e30f};
    float lst[4] = {0.f, 0.f, 0.f, 0.f};
    const float scale = 0.0625f;   // 1/sqrt(256)

    for (int j = 0; j < 16; j++) {
        // stage K tile j, fragment order, async (zero VGPR cost).
        // slot s=(ct*8+kc): lane (quad,l16) -> K[kv=j*64+ct*16+l16][feat=quad*8+kc*32 ..+8]
        #pragma unroll
        for (int s4 = 0; s4 < 4; s4++) {
            int slot = w * 4 + s4;
            int ct = slot >> 3, kc = slot & 7;
            size_t go = (size_t)(j * 64 + ct * 16 + l16) * N_ + quad * 8 + kc * 32;
            gload_lds16(qhb + go, &K_h[slot * 512]);
            gload_lds16(qlb + go, &K_l[slot * 512]);
        }
        __syncthreads();

        // QK^T, split 3-term: wave w owns q rows w*16..+16, all 64 kv cols
        floatx4 sc[4];
        #pragma unroll
        for (int ct = 0; ct < 4; ct++) {
            floatx4 acc = (floatx4){0.f, 0.f, 0.f, 0.f};
            #pragma unroll
            for (int kc = 0; kc < 8; kc++) {
                short8_t bkh = *(const short8_t*)&K_h[(ct * 8 + kc) * 512 + lane * 8];
                short8_t bkl = *(const short8_t*)&K_l[(ct * 8 + kc) * 512 + lane * 8];
                acc = __builtin_amdgcn_mfma_f32_16x16x32_bf16(qfh[kc], bkh, acc, 0, 0, 0);
                acc = __builtin_amdgcn_mfma_f32_16x16x32_bf16(qfh[kc], bkl, acc, 0, 0, 0);
                acc = __builtin_amdgcn_mfma_f32_16x16x32_bf16(qfl[kc], bkh, acc, 0, 0, 0);
            }
            sc[ct] = acc;
        }

        // online softmax per row (row = w*16 + quad*4 + r)
        float al[4];
        #pragma unroll
        for (int r = 0; r < 4; r++) {
            float m = fmaxf(fmaxf(sc[0][r], sc[1][r]), fmaxf(sc[2][r], sc[3][r])) * scale;
            #pragma unroll
            for (int o = 1; o < 16; o <<= 1) m = fmaxf(m, __shfl_xor(m, o));
            float Mn = fmaxf(Mst[r], m);
            float alpha = __expf(Mst[r] - Mn);
            Mst[r] = Mn;
            int row = w * 16 + quad * 4 + r;
            float rsum = 0.f;
            #pragma unroll
            for (int ct = 0; ct < 4; ct++) {
                float p = __expf(sc[ct][r] * scale - Mn);
                rsum += p;
                unsigned short ph = f2bf(p);
                P_h[row * PP + ct * 16 + l16] = ph;
                P_l[row * PP + ct * 16 + l16] = f2bf(p - bf2f(ph));
            }
            #pragma unroll
            for (int o = 1; o < 16; o <<= 1) rsum += __shfl_xor(rsum, o);
            lst[r] = lst[r] * alpha + rsum;
            al[r] = alpha;
        }
        if (l16 == 0) {
            #pragma unroll
            for (int r = 0; r < 4; r++) alpha_lds[w * 16 + quad * 4 + r] = al[r];
        }
        __syncthreads();

        // PV, split 3-term: wave w owns q-half h2, d range qw*64..+64
        #pragma unroll
        for (int mt = 0; mt < 4; mt++) {
            float af0 = alpha_lds[h2 * 64 + mt * 16 + quad * 4 + 0];
            float af1 = alpha_lds[h2 * 64 + mt * 16 + quad * 4 + 1];
            float af2 = alpha_lds[h2 * 64 + mt * 16 + quad * 4 + 2];
            float af3 = alpha_lds[h2 * 64 + mt * 16 + quad * 4 + 3];
            #pragma unroll
            for (int tn = 0; tn < 4; tn++) {
                O[mt][tn][0] *= af0; O[mt][tn][1] *= af1;
                O[mt][tn][2] *= af2; O[mt][tn][3] *= af3;
            }
        }
        short8_t vbh[4][2], vbl[4][2];
        #pragma unroll
        for (int tn = 0; tn < 4; tn++)
            #pragma unroll
            for (int kc = 0; kc < 2; kc++) {
                size_t o = (size_t)(qw * 64 + tn * 16 + l16) * T_ + j * 64 + quad * 8 + kc * 32;
                vbh[tn][kc] = *(const short8_t*)(xhb + o);
                vbl[tn][kc] = *(const short8_t*)(xlb + o);
            }
        #pragma unroll
        for (int mt = 0; mt < 4; mt++) {
            int prow = h2 * 64 + mt * 16 + l16;
            short8_t pa0h = *(const short8_t*)&P_h[prow * PP + quad * 8];
            short8_t pa1h = *(const short8_t*)&P_h[prow * PP + quad * 8 + 32];
            short8_t pa0l = *(const short8_t*)&P_l[prow * PP + quad * 8];
            short8_t pa1l = *(const short8_t*)&P_l[prow * PP + quad * 8 + 32];
            #pragma unroll
            for (int tn = 0; tn < 4; tn++) {
                O[mt][tn] = __builtin_amdgcn_mfma_f32_16x16x32_bf16(pa0h, vbh[tn][0], O[mt][tn], 0, 0, 0);
                O[mt][tn] = __builtin_amdgcn_mfma_f32_16x16x32_bf16(pa1h, vbh[tn][1], O[mt][tn], 0, 0, 0);
                O[mt][tn] = __builtin_amdgcn_mfma_f32_16x16x32_bf16(pa0h, vbl[tn][0], O[mt][tn], 0, 0, 0);
                O[mt][tn] = __builtin_amdgcn_mfma_f32_16x16x32_bf16(pa1h, vbl[tn][1], O[mt][tn], 0, 0, 0);
                O[mt][tn] = __builtin_amdgcn_mfma_f32_16x16x32_bf16(pa0l, vbh[tn][0], O[mt][tn], 0, 0, 0);
                O[mt][tn] = __builtin_amdgcn_mfma_f32_16x16x32_bf16(pa1l, vbh[tn][1], O[mt][tn], 0, 0, 0);
            }
        }
        __syncthreads();
    }

    // epilogue: yKV = LN_d(O / l), written as bf16 hi/lo
    if (l16 == 0) {
        #pragma unroll
        for (int r = 0; r < 4; r++) linv_lds[w * 16 + quad * 4 + r] = 1.f / lst[r];
    }
    #pragma unroll
    for (int mt = 0; mt < 4; mt++) {
        #pragma unroll
        for (int r = 0; r < 4; r++) {
            float a0 = O[mt][0][r], a1 = O[mt][1][r], a2 = O[mt][2][r], a3 = O[mt][3][r];
            float s1 = a0 + a1 + a2 + a3;
            float s2 = a0 * a0 + a1 * a1 + a2 * a2 + a3 * a3;
            #pragma unroll
            for (int o = 1; o < 16; o <<= 1) { s1 += __shfl_xor(s1, o); s2 += __shfl_xor(s2, o); }
            if (l16 == 0) {
                stat_lds[0][h2 * 64 + mt * 16 + quad * 4 + r][qw] = s1;
                stat_lds[1][h2 * 64 + mt * 16 + quad * 4 + r][qw] = s2;
            }
        }
    }
    __syncthreads();
    if (tid < 128) {
        float li = linv_lds[tid];
        float S1 = stat_lds[0][tid][0] + stat_lds[0][tid][1] + stat_lds[0][tid][2] + stat_lds[0][tid][3];
        float S2 = stat_lds[1][tid][0] + stat_lds[1][tid][1] + stat_lds[1][tid][2] + stat_lds[1][tid][3];
        float mean = S1 * li * (1.f / 256.f);
        float e2   = S2 * li * li * (1.f / 256.f);
        float var  = e2 - mean * mean;
        float rs = rsqrtf(var + EPS_);
        ab_lds[0][tid] = li * rs;
        ab_lds[1][tid] = mean * rs;
    }
    __syncthreads();
    size_t obase = ((size_t)bh * T_ + t0q) * D_;
    #pragma unroll
    for (int mt = 0; mt < 4; mt++) {
        #pragma unroll
        for (int r = 0; r < 4; r++) {
            int row = h2 * 64 + mt * 16 + quad * 4 + r;
            float a = ab_lds[0][row], bb = ab_lds[1][row];
            #pragma unroll
            for (int tn = 0; tn < 4; tn++) {
                float v = O[mt][tn][r] * a - bb;
                size_t o = obase + (size_t)row * D_ + qw * 64 + tn * 16 + l16;
                unsigned short hb = f2bf(v);
                ykvh[o] = hb;
                ykvl[o] = f2bf(v - bf2f(hb));
            }
        }
    }
}

// ---------- residual + double LN (+ bf16 hi/lo split of x) ----------
__global__ __launch_bounds__(256) void k_resid_ln(float* __restrict__ x,
                                                  const float* __restrict__ ymlp,
                                                  unsigned short* __restrict__ xh,
                                                  unsigned short* __restrict__ xl)
{
    __shared__ float red[8];
    int row = blockIdx.x, d = threadIdx.x;
    size_t o = (size_t)row * D_ + d;
    float y = ymlp[o];
    float2 mv1 = block_stats_256(y, red);
    float v = x[o] + (y - mv1.x) * rsqrtf(mv1.y + EPS_);
    float2 mv2 = block_stats_256(v, red);
    float out = (v - mv2.x) * rsqrtf(mv2.y + EPS_);
    x[o] = out;
    unsigned short hb = f2bf(out);
    xh[o] = hb;
    xl[o] = f2bf(out - bf2f(hb));
}

// ---------- logits ----------
__global__ __launch_bounds__(256) void k_logits(
    const float* __restrict__ x, const float* __restrict__ out_w,
    const float* __restrict__ out_b, float* __restrict__ out)
{
    __shared__ float red[4];
    int row = blockIdx.x, d = threadIdx.x;
    float v = x[(size_t)row * D_ + d] * out_w[d];
    #pragma unroll
    for (int o = 32; o > 0; o >>= 1) v += __shfl_down(v, o);
    int wave = d >> 6, lane = d & 63;
    if (lane == 0) red[wave] = v;
    __syncthreads();
    if (d == 0) out[row] = red[0] + red[1] + red[2] + red[3] + out_b[0];
}

extern "C" void kernel_launch(void* const* d_in, const int* in_sizes, int n_in,
                              void* d_out, int out_size, void* d_ws, size_t ws_size,
                              hipStream_t stream)
{
    (void)in_sizes; (void)n_in; (void)out_size;
    if (ws_size < ((size_t)115 << 20)) return;

    const float* inputs    = (const float*)d_in[0];
    const float* in_w      = (const float*)d_in[1];
    const float* in_b      = (const float*)d_in[2];
    const float* encoder   = (const float*)d_in[3];
    const float* encoder_v = (const float*)d_in[4];
    const float* decoder   = (const float*)d_in[5];
    const float* out_w     = (const float*)d_in[6];
    const float* out_b     = (const float*)d_in[7];

    char* wsb = (char*)d_ws;
    float* x             = (float*)(wsb);                                 //  8 MB fp32 (B,T,D)
    unsigned short* x_h  = (unsigned short*)(wsb + ((size_t)8  << 20));   //  4 MB bf16 (B,T,D) hi
    unsigned short* x_l  = (unsigned short*)(wsb + ((size_t)12 << 20));   //  4 MB lo
    unsigned short* xT_h = x_h;                                           //  ALIAS (disjoint phases)
    unsigned short* xT_l = x_l;
    unsigned short* xs_h = (unsigned short*)(wsb + ((size_t)16 << 20));   // 16 MB (B,T,NH*N) hi
    unsigned short* xs_l = (unsigned short*)(wsb + ((size_t)32 << 20));   // 16 MB lo
    float* ymlp          = (float*)(wsb + ((size_t)16 << 20));            //  8 MB fp32, ALIASES xs_h
    unsigned short* qr_h = (unsigned short*)(wsb + ((size_t)48 << 20));   // 16 MB (B,NH,T,N) hi
    unsigned short* qr_l = (unsigned short*)(wsb + ((size_t)64 << 20));   // 16 MB lo
    unsigned short* xy_h = qr_h;                                          //  ALIAS: xy after attn
    unsigned short* xy_l = qr_l;
    unsigned short* ykv_h = (unsigned short*)(wsb + ((size_t)80 << 20));  // 16 MB (B,NH,T,D) hi
    unsigned short* ykv_l = (unsigned short*)(wsb + ((size_t)96 << 20));  // 16 MB lo
    char* wbase = wsb + ((size_t)112 << 20);                              //  3 MB weights
    unsigned short* encT_h = (unsigned short*)(wbase);
    unsigned short* encT_l = (unsigned short*)(wbase + 0x80000);
    unsigned short* evT_h  = (unsigned short*)(wbase + 2 * 0x80000);
    unsigned short* evT_l  = (unsigned short*)(wbase + 3 * 0x80000);
    unsigned short* decT_h = (unsigned short*)(wbase + 4 * 0x80000);
    unsigned short* decT_l = (unsigned short*)(wbase + 5 * 0x80000);

    k_wT<<<dim3(4, 4, 4), 256, 0, stream>>>(encoder,   encT_h, encT_l, 256, 256);
    k_wT<<<dim3(4, 4, 4), 256, 0, stream>>>(encoder_v, evT_h,  evT_l,  256, 256);
    k_wT<<<dim3(4, 16, 1), 256, 0, stream>>>(decoder,  decT_h, decT_l, 1024, 256);

    k_input_ln<<<B_ * T_, 256, 0, stream>>>(inputs, in_w, in_b, x, x_h, x_l);
    for (int l = 0; l < 3; l++) {
        k_gemm_mfma<0><<<dim3(8, 64, 1), 256, 0, stream>>>(
            x_h, x_l, encT_h, encT_l, nullptr, nullptr, xs_h, xs_l, nullptr);
        k_rope_bf16<<<4096, 256, 0, stream>>>(xs_h, xs_l, qr_h, qr_l);
        k_xT<<<dim3(16, 4, 8), 256, 0, stream>>>(x, xT_h, xT_l);
        k_attn_mfma<<<256, 512, 0, stream>>>(qr_h, qr_l, xT_h, xT_l, ykv_h, ykv_l);
        k_gemm_mfma<1><<<dim3(2, 8, 32), 256, 0, stream>>>(
            ykv_h, ykv_l, evT_h, evT_l, xs_h, xs_l, xy_h, xy_l, nullptr);
        k_gemm_mfma<2><<<dim3(2, 64, 1), 256, 0, stream>>>(
            xy_h, xy_l, decT_h, decT_l, nullptr, nullptr, nullptr, nullptr, ymlp);
        k_resid_ln<<<B_ * T_, 256, 0, stream>>>(x, ymlp, x_h, x_l);
    }
    k_logits<<<B_ * T_, 256, 0, stream>>>(x, out_w, out_b, (float*)d_out);
}

// Round 8
// 941.017 us; speedup vs baseline: 2.7001x; 1.1403x over previous
//
#include <hip/hip_runtime.h>
#include <hip/hip_bf16.h>
#include <math.h>

#define B_ 8
#define T_ 1024
#define D_ 256
#define NH_ 4
#define N_ 256
#define EPS_ 1e-5f

typedef __attribute__((ext_vector_type(8))) short short8_t;
typedef __attribute__((ext_vector_type(4))) float floatx4;

__device__ inline unsigned short f2bf(float f) {
    unsigned u = __builtin_bit_cast(unsigned, f);
    u += 0x7FFFu + ((u >> 16) & 1u);          // round-to-nearest-even
    return (unsigned short)(u >> 16);
}
__device__ inline float bf2f(unsigned short h) {
    return __builtin_bit_cast(float, (unsigned)h << 16);
}

// async global->LDS, 16 B per lane; lds base wave-uniform, HW adds lane*16
__device__ inline void gload_lds16(const unsigned short* g, unsigned short* l) {
    __builtin_amdgcn_global_load_lds(
        (const __attribute__((address_space(1))) unsigned int*)g,
        (__attribute__((address_space(3))) unsigned int*)l, 16, 0, 0);
}

// ---------- helpers ----------
__device__ inline float2 block_stats_256(float v, float* red) {
    float s1 = v, s2 = v * v;
    #pragma unroll
    for (int o = 32; o > 0; o >>= 1) { s1 += __shfl_down(s1, o); s2 += __shfl_down(s2, o); }
    int wave = threadIdx.x >> 6, lane = threadIdx.x & 63;
    __syncthreads();
    if (lane == 0) { red[wave] = s1; red[4 + wave] = s2; }
    __syncthreads();
    float S1 = red[0] + red[1] + red[2] + red[3];
    float S2 = red[4] + red[5] + red[6] + red[7];
    float mean = S1 * (1.f / 256.f);
    float var  = S2 * (1.f / 256.f) - mean * mean;
    return make_float2(mean, var);
}

// ---------- weight transpose + split ----------
__global__ __launch_bounds__(256) void k_wT(
    const float* __restrict__ in, unsigned short* __restrict__ outh,
    unsigned short* __restrict__ outl, int R, int C)
{
    __shared__ float tile[64][65];
    int c0 = blockIdx.x * 64, r0 = blockIdx.y * 64, h = blockIdx.z;
    in += (size_t)h * R * C;
    for (int i = threadIdx.x; i < 4096; i += 256) {
        int r = i >> 6, c = i & 63;
        tile[r][c] = in[(size_t)(r0 + r) * C + c0 + c];
    }
    __syncthreads();
    for (int i = threadIdx.x; i < 4096; i += 256) {
        int c = i >> 6, r = i & 63;
        float v = tile[r][c];
        unsigned short hb = f2bf(v);
        size_t o = (size_t)(h * C + c0 + c) * R + r0 + r;
        outh[o] = hb;
        outl[o] = f2bf(v - bf2f(hb));
    }
}

// ---------- input projection + LN (+ bf16 hi/lo split of x) ----------
__global__ __launch_bounds__(256) void k_input_ln(
    const float* __restrict__ inputs, const float* __restrict__ in_w,
    const float* __restrict__ in_b, float* __restrict__ x,
    unsigned short* __restrict__ xh, unsigned short* __restrict__ xl)
{
    __shared__ float red[8];
    int row = blockIdx.x;
    int d = threadIdx.x;
    float v = inputs[row] * in_w[d] + in_b[d];
    float2 mv = block_stats_256(v, red);
    float o = (v - mv.x) * rsqrtf(mv.y + EPS_);
    size_t idx = (size_t)row * D_ + d;
    x[idx] = o;
    unsigned short hb = f2bf(o);
    xh[idx] = hb;
    xl[idx] = f2bf(o - bf2f(hb));
}

// ---------- split-bf16 MFMA GEMM (unchanged) ----------
#define PG 40   // LDS pitch (32 + 8)
template<int MODE>
__global__ __launch_bounds__(256, 1) void k_gemm_mfma(
    const unsigned short* __restrict__ Ah, const unsigned short* __restrict__ Al,
    const unsigned short* __restrict__ Wh, const unsigned short* __restrict__ Wl,
    const unsigned short* __restrict__ xsh, const unsigned short* __restrict__ xsl,
    unsigned short* __restrict__ outh, unsigned short* __restrict__ outl,
    float* __restrict__ outf)
{
    constexpr int K = (MODE == 2) ? 1024 : 256;
    __shared__ unsigned short As_h[128 * PG], As_l[128 * PG];
    __shared__ unsigned short Ws_h[128 * PG], Ws_l[128 * PG];
    int tid = threadIdx.x;
    int w = tid >> 6, lane = tid & 63, quad = lane >> 4, l16 = lane & 15;
    int wm = w >> 1, wn = w & 1;
    int m0 = blockIdx.y * 128, n0x = blockIdx.x * 128;
    size_t a_row0, w_row0, out_row0;
    int col0;
    if (MODE == 1) {
        int bh = blockIdx.z;
        a_row0 = (size_t)bh * 1024 + m0;
        w_row0 = (size_t)((bh & 3) * 256 + n0x);
        out_row0 = (size_t)(bh >> 2) * 1024 + m0;
        col0 = (bh & 3) * 256 + n0x;
    } else {
        a_row0 = m0; w_row0 = n0x; out_row0 = m0; col0 = n0x;
    }
    floatx4 acc[4][4];
    #pragma unroll
    for (int mt = 0; mt < 4; mt++)
        #pragma unroll
        for (int nt = 0; nt < 4; nt++)
            acc[mt][nt] = (floatx4){0.f, 0.f, 0.f, 0.f};

    for (int k0 = 0; k0 < K; k0 += 32) {
        #pragma unroll
        for (int it = 0; it < 2; it++) {
            int fl = tid + it * 256;
            int row = fl >> 2, ch = fl & 3;
            size_t ga = (a_row0 + row) * (size_t)K + k0 + ch * 8;
            size_t gw = (w_row0 + row) * (size_t)K + k0 + ch * 8;
            *(short8_t*)&As_h[row * PG + ch * 8] = *(const short8_t*)(Ah + ga);
            *(short8_t*)&As_l[row * PG + ch * 8] = *(const short8_t*)(Al + ga);
            *(short8_t*)&Ws_h[row * PG + ch * 8] = *(const short8_t*)(Wh + gw);
            *(short8_t*)&Ws_l[row * PG + ch * 8] = *(const short8_t*)(Wl + gw);
        }
        __syncthreads();
        short8_t afh[4], afl[4], bfh[4], bfl[4];
        #pragma unroll
        for (int mt = 0; mt < 4; mt++) {
            afh[mt] = *(const short8_t*)&As_h[(wm * 64 + mt * 16 + l16) * PG + quad * 8];
            afl[mt] = *(const short8_t*)&As_l[(wm * 64 + mt * 16 + l16) * PG + quad * 8];
        }
        #pragma unroll
        for (int nt = 0; nt < 4; nt++) {
            bfh[nt] = *(const short8_t*)&Ws_h[(wn * 64 + nt * 16 + l16) * PG + quad * 8];
            bfl[nt] = *(const short8_t*)&Ws_l[(wn * 64 + nt * 16 + l16) * PG + quad * 8];
        }
        #pragma unroll
        for (int mt = 0; mt < 4; mt++)
            #pragma unroll
            for (int nt = 0; nt < 4; nt++) {
                acc[mt][nt] = __builtin_amdgcn_mfma_f32_16x16x32_bf16(afh[mt], bfh[nt], acc[mt][nt], 0, 0, 0);
                acc[mt][nt] = __builtin_amdgcn_mfma_f32_16x16x32_bf16(afh[mt], bfl[nt], acc[mt][nt], 0, 0, 0);
                acc[mt][nt] = __builtin_amdgcn_mfma_f32_16x16x32_bf16(afl[mt], bfh[nt], acc[mt][nt], 0, 0, 0);
            }
        __syncthreads();
    }

    #pragma unroll
    for (int mt = 0; mt < 4; mt++) {
        #pragma unroll
        for (int r = 0; r < 4; r++) {
            size_t grow = out_row0 + wm * 64 + mt * 16 + quad * 4 + r;
            #pragma unroll
            for (int nt = 0; nt < 4; nt++) {
                int gcol = col0 + wn * 64 + nt * 16 + l16;
                float v = acc[mt][nt][r];
                if (MODE == 0) {
                    v = fmaxf(v, 0.f);
                    size_t o = grow * 1024 + gcol;
                    unsigned short hb = f2bf(v);
                    outh[o] = hb;
                    outl[o] = f2bf(v - bf2f(hb));
                } else if (MODE == 1) {
                    float y = fmaxf(v, 0.f);
                    size_t o = grow * 1024 + gcol;
                    float xv = bf2f(xsh[o]) + bf2f(xsl[o]);
                    float p = xv * y;
                    unsigned short hb = f2bf(p);
                    outh[o] = hb;
                    outl[o] = f2bf(p - bf2f(hb));
                } else {
                    outf[grow * 256 + gcol] = v;
                }
            }
        }
    }
}

// ---------- rope: xs hi/lo (B,T,NH,N) -> qr hi/lo (B,NH,T,N) bf16 ----------
__global__ __launch_bounds__(256) void k_rope_bf16(
    const unsigned short* __restrict__ xsh, const unsigned short* __restrict__ xsl,
    unsigned short* __restrict__ qh, unsigned short* __restrict__ ql)
{
    int tid = blockIdx.x * 256 + threadIdx.x;
    int e0 = tid * 8;
    int n0 = e0 & 255;
    int t  = (e0 >> 8) & 1023;
    int bh = e0 >> 18;
    int h = bh & 3, b = bh >> 2;
    size_t src = (((size_t)(b * T_ + t) * NH_ + h) << 8) + n0;
    short8_t vh = *(const short8_t*)(xsh + src);
    short8_t vl = *(const short8_t*)(xsl + src);
    float v[8];
    #pragma unroll
    for (int i = 0; i < 8; i++)
        v[i] = bf2f((unsigned short)vh[i]) + bf2f((unsigned short)vl[i]);
    float cc[4], ss[4];
    int p0 = n0 >> 1;
    #pragma unroll
    for (int i = 0; i < 4; i++) {
        int p = p0 + i;
        int j = p & 63;
        int pos = (p < 64) ? (t & 31) : (t >> 5);
        float f = powf(10000.f, -(float)j * (1.f / 64.f));
        float ang = (float)pos * f;
        sincosf(ang, &ss[i], &cc[i]);
    }
    float r[8];
    r[0] = v[0] * cc[0] - v[1] * ss[0];
    r[1] = v[0] * ss[0] + v[1] * cc[0];
    r[2] = v[2] * cc[1] - v[3] * ss[1];
    r[3] = v[2] * ss[1] + v[3] * cc[1];
    r[4] = v[4] * cc[2] - v[5] * ss[2];
    r[5] = v[4] * ss[2] + v[5] * cc[2];
    r[6] = v[6] * cc[3] - v[7] * ss[3];
    r[7] = v[6] * ss[3] + v[7] * cc[3];
    short8_t oh, ol;
    #pragma unroll
    for (int i = 0; i < 8; i++) {
        unsigned short hbits = f2bf(r[i]);
        oh[i] = (short)hbits;
        ol[i] = (short)f2bf(r[i] - bf2f(hbits));
    }
    *(short8_t*)(qh + e0) = oh;
    *(short8_t*)(ql + e0) = ol;
}

// ---------- x (B,T,D) fp32 -> Vf hi/lo fragment-order bf16 ----------
// Vf[b][jj][tn][lane*8+i] = x[b][t = jj*32 + (lane>>4)*8 + i][d = tn*16 + (lane&15)]
// so attention's PV B-fragment is one contiguous 1 KB wave read.
__global__ __launch_bounds__(256) void k_xT(const float* __restrict__ x,
                                            unsigned short* __restrict__ Vfh,
                                            unsigned short* __restrict__ Vfl)
{
    __shared__ float tile[64][65];   // [t_local][d_local]
    int t0 = blockIdx.x * 64, d0 = blockIdx.y * 64, b = blockIdx.z;
    const float* src = x + ((size_t)b * T_ + t0) * D_ + d0;
    for (int i = threadIdx.x; i < 1024; i += 256) {
        int r = i >> 4, c = i & 15;
        float4 v = *(const float4*)(src + (size_t)r * D_ + c * 4);
        tile[r][c * 4 + 0] = v.x;
        tile[r][c * 4 + 1] = v.y;
        tile[r][c * 4 + 2] = v.z;
        tile[r][c * 4 + 3] = v.w;
    }
    __syncthreads();
    for (int i = threadIdx.x; i < 1024; i += 256) {
        int d = i >> 4, c = i & 15;          // d_local, t-group (4 consecutive t)
        int tg = t0 + c * 4;
        int jj = tg >> 5, qd = (tg >> 3) & 3, i8 = tg & 7;   // i8 in {0,4}
        int dg = d0 + d;
        int tn = dg >> 4, s16 = dg & 15;
        size_t o = (((size_t)b * 32 + jj) * 16 + tn) * 512 + (qd * 16 + s16) * 8 + i8;
        float v0 = tile[c * 4 + 0][d], v1 = tile[c * 4 + 1][d];
        float v2 = tile[c * 4 + 2][d], v3 = tile[c * 4 + 3][d];
        ushort4 oh, ol;
        oh.x = f2bf(v0); ol.x = f2bf(v0 - bf2f(oh.x));
        oh.y = f2bf(v1); ol.y = f2bf(v1 - bf2f(oh.y));
        oh.z = f2bf(v2); ol.z = f2bf(v2 - bf2f(oh.z));
        oh.w = f2bf(v3); ol.w = f2bf(v3 - bf2f(oh.w));
        *(ushort4*)(Vfh + o) = oh;
        *(ushort4*)(Vfl + o) = ol;
    }
}

// ---------- fused split-bf16 MFMA flash attention + /l + LayerNorm ----------
// block = (b,h, 128 q), 8 waves; wave owns 16 q rows END-TO-END (16 q x 256 d).
// P/alpha/l/LN all intra-wave -> ONE barrier per step. K double-buffered in
// LDS (kv=32 tiles) via global_load_lds: loads for j+1 issued right after the
// barrier, land during step-j compute (latency hidden). V read from global in
// fragment order (1 KB coalesced per wave-read, L2-resident).
#define PPW 36   // per-wave P pitch (32 + 4)

__global__ __launch_bounds__(512, 1) void k_attn_mfma(
    const unsigned short* __restrict__ qr_h, const unsigned short* __restrict__ qr_l,
    const unsigned short* __restrict__ Vf_h, const unsigned short* __restrict__ Vf_l,
    unsigned short* __restrict__ ykvh, unsigned short* __restrict__ ykvl)
{
    __shared__ unsigned short K_h[2][16 * 512];   // 32 KB (2 buf, frag order)
    __shared__ unsigned short K_l[2][16 * 512];   // 32 KB
    __shared__ unsigned short P_h[8][16 * PPW];   // 9216 B (per-wave private)
    __shared__ unsigned short P_l[8][16 * PPW];   // 9216 B

    int tid = threadIdx.x;
    int w = tid >> 6, lane = tid & 63, quad = lane >> 4, l16 = lane & 15;
    int gid = blockIdx.x;
    int bh = gid & 31, tile = gid >> 5, b = bh >> 2;   // XCD swizzle
    int t0q = tile * 128;
    const unsigned short* qhb = qr_h + (size_t)bh * T_ * N_;
    const unsigned short* qlb = qr_l + (size_t)bh * T_ * N_;
    const unsigned short* vhb = Vf_h + (size_t)b * 32 * 16 * 512;
    const unsigned short* vlb = Vf_l + (size_t)b * 32 * 16 * 512;

    // Q A-frags: wave's 16 rows, full feature dim (8 kc chunks), hi+lo
    short8_t qfh[8], qfl[8];
    #pragma unroll
    for (int kc = 0; kc < 8; kc++) {
        size_t o = (size_t)(t0q + w * 16 + l16) * N_ + kc * 32 + quad * 8;
        qfh[kc] = *(const short8_t*)(qhb + o);
        qfl[kc] = *(const short8_t*)(qlb + o);
    }

    floatx4 O[16];
    #pragma unroll
    for (int tn = 0; tn < 16; tn++) O[tn] = (floatx4){0.f, 0.f, 0.f, 0.f};
    float Mst[4] = {-1e30f, -1e30f, -1e30f, -1e30f};
    float lst[4] = {0.f, 0.f, 0.f, 0.f};
    const float scale = 0.0625f;   // 1/sqrt(256)

    // preamble: stage kv tile 0 into buffer 0 (wave w stages slots 2w, 2w+1)
    #pragma unroll
    for (int s = 0; s < 2; s++) {
        int slot = w * 2 + s;
        int ct = slot >> 3, kc = slot & 7;
        size_t go = (size_t)(ct * 16 + l16) * N_ + kc * 32 + quad * 8;
        gload_lds16(qhb + go, &K_h[0][slot * 512]);
        gload_lds16(qlb + go, &K_l[0][slot * 512]);
    }

    for (int j = 0; j < 32; j++) {
        int buf = j & 1;
        __syncthreads();            // K tile j ready; buf^1 free (read in j-1 done)
        if (j < 31) {               // async-stage tile j+1 (overlaps full step-j compute)
            #pragma unroll
            for (int s = 0; s < 2; s++) {
                int slot = w * 2 + s;
                int ct = slot >> 3, kc = slot & 7;
                size_t go = (size_t)((j + 1) * 32 + ct * 16 + l16) * N_ + kc * 32 + quad * 8;
                gload_lds16(qhb + go, &K_h[buf ^ 1][slot * 512]);
                gload_lds16(qlb + go, &K_l[buf ^ 1][slot * 512]);
            }
        }

        // QK^T (split 3-term): 16 q rows x 32 kv cols
        floatx4 sc[2];
        #pragma unroll
        for (int ct = 0; ct < 2; ct++) {
            floatx4 acc = (floatx4){0.f, 0.f, 0.f, 0.f};
            #pragma unroll
            for (int kc = 0; kc < 8; kc++) {
                short8_t bkh = *(const short8_t*)&K_h[buf][(ct * 8 + kc) * 512 + lane * 8];
                short8_t bkl = *(const short8_t*)&K_l[buf][(ct * 8 + kc) * 512 + lane * 8];
                acc = __builtin_amdgcn_mfma_f32_16x16x32_bf16(qfh[kc], bkh, acc, 0, 0, 0);
                acc = __builtin_amdgcn_mfma_f32_16x16x32_bf16(qfh[kc], bkl, acc, 0, 0, 0);
                acc = __builtin_amdgcn_mfma_f32_16x16x32_bf16(qfl[kc], bkh, acc, 0, 0, 0);
            }
            sc[ct] = acc;
        }

        // online softmax — fully intra-wave (row = w*16 + quad*4 + r)
        #pragma unroll
        for (int r = 0; r < 4; r++) {
            float m = fmaxf(sc[0][r], sc[1][r]) * scale;
            #pragma unroll
            for (int o = 1; o < 16; o <<= 1) m = fmaxf(m, __shfl_xor(m, o));
            float Mn = fmaxf(Mst[r], m);
            float alpha = __expf(Mst[r] - Mn);
            Mst[r] = Mn;
            float rsum = 0.f;
            #pragma unroll
            for (int ct = 0; ct < 2; ct++) {
                float p = __expf(sc[ct][r] * scale - Mn);
                rsum += p;
                unsigned short ph = f2bf(p);
                P_h[w][(quad * 4 + r) * PPW + ct * 16 + l16] = ph;
                P_l[w][(quad * 4 + r) * PPW + ct * 16 + l16] = f2bf(p - bf2f(ph));
            }
            #pragma unroll
            for (int o = 1; o < 16; o <<= 1) rsum += __shfl_xor(rsum, o);
            lst[r] = lst[r] * alpha + rsum;
            #pragma unroll
            for (int tn = 0; tn < 16; tn++) O[tn][r] *= alpha;
        }

        // P C-layout -> A-layout via same-wave LDS round-trip (no barrier)
        short8_t pah = *(const short8_t*)&P_h[w][l16 * PPW + quad * 8];
        short8_t pal = *(const short8_t*)&P_l[w][l16 * PPW + quad * 8];

        // PV (split 3-term): V frags from global, fragment order, 1 KB/read
        #pragma unroll
        for (int tn = 0; tn < 16; tn++) {
            size_t vo = ((size_t)(j * 16 + tn) << 9) + lane * 8;
            short8_t vbh = *(const short8_t*)(vhb + vo);
            short8_t vbl = *(const short8_t*)(vlb + vo);
            O[tn] = __builtin_amdgcn_mfma_f32_16x16x32_bf16(pah, vbh, O[tn], 0, 0, 0);
            O[tn] = __builtin_amdgcn_mfma_f32_16x16x32_bf16(pah, vbl, O[tn], 0, 0, 0);
            O[tn] = __builtin_amdgcn_mfma_f32_16x16x32_bf16(pal, vbh, O[tn], 0, 0, 0);
        }
    }

    // epilogue: yKV = LN_d(O / l) — fully intra-wave, bf16 hi/lo out
    size_t obase = ((size_t)bh * T_ + t0q + w * 16) * D_;
    #pragma unroll
    for (int r = 0; r < 4; r++) {
        float li = 1.f / lst[r];
        float s1 = 0.f, s2 = 0.f;
        #pragma unroll
        for (int tn = 0; tn < 16; tn++) { float v = O[tn][r]; s1 += v; s2 += v * v; }
        #pragma unroll
        for (int o = 1; o < 16; o <<= 1) { s1 += __shfl_xor(s1, o); s2 += __shfl_xor(s2, o); }
        float mean = s1 * li * (1.f / 256.f);
        float e2   = s2 * li * li * (1.f / 256.f);
        float var  = e2 - mean * mean;
        float rs = rsqrtf(var + EPS_);
        float a = li * rs, bb = mean * rs;
        int row = quad * 4 + r;
        #pragma unroll
        for (int tn = 0; tn < 16; tn++) {
            float v = O[tn][r] * a - bb;
            size_t o = obase + (size_t)row * D_ + tn * 16 + l16;
            unsigned short hb = f2bf(v);
            ykvh[o] = hb;
            ykvl[o] = f2bf(v - bf2f(hb));
        }
    }
}

// ---------- residual + double LN (+ bf16 hi/lo split of x) ----------
__global__ __launch_bounds__(256) void k_resid_ln(float* __restrict__ x,
                                                  const float* __restrict__ ymlp,
                                                  unsigned short* __restrict__ xh,
                                                  unsigned short* __restrict__ xl)
{
    __shared__ float red[8];
    int row = blockIdx.x, d = threadIdx.x;
    size_t o = (size_t)row * D_ + d;
    float y = ymlp[o];
    float2 mv1 = block_stats_256(y, red);
    float v = x[o] + (y - mv1.x) * rsqrtf(mv1.y + EPS_);
    float2 mv2 = block_stats_256(v, red);
    float out = (v - mv2.x) * rsqrtf(mv2.y + EPS_);
    x[o] = out;
    unsigned short hb = f2bf(out);
    xh[o] = hb;
    xl[o] = f2bf(out - bf2f(hb));
}

// ---------- logits ----------
__global__ __launch_bounds__(256) void k_logits(
    const float* __restrict__ x, const float* __restrict__ out_w,
    const float* __restrict__ out_b, float* __restrict__ out)
{
    __shared__ float red[4];
    int row = blockIdx.x, d = threadIdx.x;
    float v = x[(size_t)row * D_ + d] * out_w[d];
    #pragma unroll
    for (int o = 32; o > 0; o >>= 1) v += __shfl_down(v, o);
    int wave = d >> 6, lane = d & 63;
    if (lane == 0) red[wave] = v;
    __syncthreads();
    if (d == 0) out[row] = red[0] + red[1] + red[2] + red[3] + out_b[0];
}

extern "C" void kernel_launch(void* const* d_in, const int* in_sizes, int n_in,
                              void* d_out, int out_size, void* d_ws, size_t ws_size,
                              hipStream_t stream)
{
    (void)in_sizes; (void)n_in; (void)out_size;
    if (ws_size < ((size_t)115 << 20)) return;

    const float* inputs    = (const float*)d_in[0];
    const float* in_w      = (const float*)d_in[1];
    const float* in_b      = (const float*)d_in[2];
    const float* encoder   = (const float*)d_in[3];
    const float* encoder_v = (const float*)d_in[4];
    const float* decoder   = (const float*)d_in[5];
    const float* out_w     = (const float*)d_in[6];
    const float* out_b     = (const float*)d_in[7];

    char* wsb = (char*)d_ws;
    float* x             = (float*)(wsb);                                 //  8 MB fp32 (B,T,D)
    unsigned short* x_h  = (unsigned short*)(wsb + ((size_t)8  << 20));   //  4 MB bf16 hi
    unsigned short* x_l  = (unsigned short*)(wsb + ((size_t)12 << 20));   //  4 MB lo
    unsigned short* Vf_h = x_h;                                           //  ALIAS (disjoint phases)
    unsigned short* Vf_l = x_l;
    unsigned short* xs_h = (unsigned short*)(wsb + ((size_t)16 << 20));   // 16 MB (B,T,NH*N) hi
    unsigned short* xs_l = (unsigned short*)(wsb + ((size_t)32 << 20));   // 16 MB lo
    float* ymlp          = (float*)(wsb + ((size_t)16 << 20));            //  8 MB fp32, ALIASES xs_h
    unsigned short* qr_h = (unsigned short*)(wsb + ((size_t)48 << 20));   // 16 MB (B,NH,T,N) hi
    unsigned short* qr_l = (unsigned short*)(wsb + ((size_t)64 << 20));   // 16 MB lo
    unsigned short* xy_h = qr_h;                                          //  ALIAS: xy after attn
    unsigned short* xy_l = qr_l;
    unsigned short* ykv_h = (unsigned short*)(wsb + ((size_t)80 << 20));  // 16 MB (B,NH,T,D) hi
    unsigned short* ykv_l = (unsigned short*)(wsb + ((size_t)96 << 20));  // 16 MB lo
    char* wbase = wsb + ((size_t)112 << 20);                              //  3 MB weights
    unsigned short* encT_h = (unsigned short*)(wbase);
    unsigned short* encT_l = (unsigned short*)(wbase + 0x80000);
    unsigned short* evT_h  = (unsigned short*)(wbase + 2 * 0x80000);
    unsigned short* evT_l  = (unsigned short*)(wbase + 3 * 0x80000);
    unsigned short* decT_h = (unsigned short*)(wbase + 4 * 0x80000);
    unsigned short* decT_l = (unsigned short*)(wbase + 5 * 0x80000);

    k_wT<<<dim3(4, 4, 4), 256, 0, stream>>>(encoder,   encT_h, encT_l, 256, 256);
    k_wT<<<dim3(4, 4, 4), 256, 0, stream>>>(encoder_v, evT_h,  evT_l,  256, 256);
    k_wT<<<dim3(4, 16, 1), 256, 0, stream>>>(decoder,  decT_h, decT_l, 1024, 256);

    k_input_ln<<<B_ * T_, 256, 0, stream>>>(inputs, in_w, in_b, x, x_h, x_l);
    for (int l = 0; l < 3; l++) {
        k_gemm_mfma<0><<<dim3(8, 64, 1), 256, 0, stream>>>(
            x_h, x_l, encT_h, encT_l, nullptr, nullptr, xs_h, xs_l, nullptr);
        k_rope_bf16<<<4096, 256, 0, stream>>>(xs_h, xs_l, qr_h, qr_l);
        k_xT<<<dim3(16, 4, 8), 256, 0, stream>>>(x, Vf_h, Vf_l);
        k_attn_mfma<<<256, 512, 0, stream>>>(qr_h, qr_l, Vf_h, Vf_l, ykv_h, ykv_l);
        k_gemm_mfma<1><<<dim3(2, 8, 32), 256, 0, stream>>>(
            ykv_h, ykv_l, evT_h, evT_l, xs_h, xs_l, xy_h, xy_l, nullptr);
        k_gemm_mfma<2><<<dim3(2, 64, 1), 256, 0, stream>>>(
            xy_h, xy_l, decT_h, decT_l, nullptr, nullptr, nullptr, nullptr, ymlp);
        k_resid_ln<<<B_ * T_, 256, 0, stream>>>(x, ymlp, x_h, x_l);
    }
    k_logits<<<B_ * T_, 256, 0, stream>>>(x, out_w, out_b, (float*)d_out);
}